// Round 1
// baseline (3315.712 us; speedup 1.0000x reference)
//
#include <hip/hip_runtime.h>
#include <hip/hip_bf16.h>

#define NN 100000
#define FIN 512
#define HID 512
#define NC 40
#define NE 1600000
#define KITER 10

// ---------------- graph build ----------------

__global__ void count_edges(const int* __restrict__ row, int* __restrict__ degc, int e) {
    for (int i = blockIdx.x * blockDim.x + threadIdx.x; i < e; i += gridDim.x * blockDim.x)
        atomicAdd(&degc[row[i]], 1);
}

__global__ void compute_dinv(const int* __restrict__ degc, float* __restrict__ dinv, int n) {
    int g = blockIdx.x * blockDim.x + threadIdx.x;
    if (g < n) dinv[g] = 1.0f / sqrtf((float)(degc[g] + 1));  // +1 self-loop
}

__global__ void scan_block(const int* __restrict__ in, int* __restrict__ outExc,
                           int* __restrict__ bsum, int n) {
    __shared__ int s[256];
    int t = threadIdx.x, g = blockIdx.x * 256 + t;
    int v = (g < n) ? in[g] : 0;
    s[t] = v; __syncthreads();
    for (int off = 1; off < 256; off <<= 1) {
        int x = (t >= off) ? s[t - off] : 0;
        __syncthreads();
        s[t] += x;
        __syncthreads();
    }
    if (g < n) outExc[g] = s[t] - v;
    if (t == 255) bsum[blockIdx.x] = s[255];
}

__global__ void scan_small(int* __restrict__ data, int n) {  // n <= 512, exclusive in-place
    __shared__ int s[512];
    int t = threadIdx.x;
    int v = (t < n) ? data[t] : 0;
    s[t] = v; __syncthreads();
    for (int off = 1; off < 512; off <<= 1) {
        int x = (t >= off) ? s[t - off] : 0;
        __syncthreads();
        s[t] += x;
        __syncthreads();
    }
    if (t < n) data[t] = s[t] - v;
}

__global__ void scan_add(int* __restrict__ rp, const int* __restrict__ bsum,
                         int* __restrict__ cur, int n, int total) {
    int g = blockIdx.x * 256 + threadIdx.x;
    if (g < n) {
        int v = rp[g] + bsum[blockIdx.x];
        rp[g] = v;
        cur[g] = v;
    }
    if (g == 0) rp[n] = total;
}

__global__ void scatter_edges(const int* __restrict__ row, const int* __restrict__ col,
                              const float* __restrict__ dinv, int* __restrict__ cur,
                              int* __restrict__ cols, float* __restrict__ wst, int e) {
    for (int i = blockIdx.x * blockDim.x + threadIdx.x; i < e; i += gridDim.x * blockDim.x) {
        int r = row[i], c = col[i];
        int slot = atomicAdd(&cur[r], 1);
        cols[slot] = c;
        wst[slot] = dinv[r] * dinv[c];
    }
}

// ---------------- MLP ----------------
// GEMM1: H[rows,512] = relu(X[rows,512] @ W1[512,512] + b1)
// block tile 128x128, BK=16, 256 threads, 8x8 per thread.
__global__ __launch_bounds__(256) void gemm1(const float* __restrict__ A,
                                             const float* __restrict__ W,
                                             const float* __restrict__ b1,
                                             float* __restrict__ H,
                                             int row_start, int row_end) {
    __shared__ float As[16][128 + 4];
    __shared__ float Bs[16][128];
    const int tid = threadIdx.x;
    const int row0 = row_start + blockIdx.y * 128;
    const int n0 = blockIdx.x * 128;
    const int tm0 = (tid >> 4) * 8;
    const int tn0 = (tid & 15) * 8;
    float acc[8][8] = {};

    const int arow = tid >> 2;         // 0..63
    const int ak = (tid & 3) * 4;      // 0,4,8,12
    const int bk = tid >> 5;           // 0..7
    const int bnl = (tid & 31) * 4;    // 0..124

    for (int k0 = 0; k0 < 512; k0 += 16) {
        #pragma unroll
        for (int h = 0; h < 2; ++h) {
            int r = row0 + arow + h * 64;
            int rc = min(r, NN - 1);
            float4 v = *(const float4*)&A[(size_t)rc * 512 + k0 + ak];
            As[ak + 0][arow + h * 64] = v.x;
            As[ak + 1][arow + h * 64] = v.y;
            As[ak + 2][arow + h * 64] = v.z;
            As[ak + 3][arow + h * 64] = v.w;
        }
        #pragma unroll
        for (int h = 0; h < 2; ++h) {
            int kr = k0 + bk + h * 8;
            *(float4*)&Bs[bk + h * 8][bnl] = *(const float4*)&W[(size_t)kr * 512 + n0 + bnl];
        }
        __syncthreads();
        #pragma unroll
        for (int kk = 0; kk < 16; ++kk) {
            float a[8], b[8];
            *(float4*)&a[0] = *(const float4*)&As[kk][tm0];
            *(float4*)&a[4] = *(const float4*)&As[kk][tm0 + 4];
            *(float4*)&b[0] = *(const float4*)&Bs[kk][tn0];
            *(float4*)&b[4] = *(const float4*)&Bs[kk][tn0 + 4];
            #pragma unroll
            for (int i = 0; i < 8; ++i)
                #pragma unroll
                for (int j = 0; j < 8; ++j)
                    acc[i][j] = fmaf(a[i], b[j], acc[i][j]);
        }
        __syncthreads();
    }
    float bb[8];
    *(float4*)&bb[0] = *(const float4*)&b1[n0 + tn0];
    *(float4*)&bb[4] = *(const float4*)&b1[n0 + tn0 + 4];
    #pragma unroll
    for (int i = 0; i < 8; ++i) {
        int r = row0 + tm0 + i;
        if (r < row_end) {
            float o[8];
            #pragma unroll
            for (int j = 0; j < 8; ++j) o[j] = fmaxf(acc[i][j] + bb[j], 0.0f);
            *(float4*)&H[(size_t)(r - row_start) * 512 + n0 + tn0] = *(float4*)&o[0];
            *(float4*)&H[(size_t)(r - row_start) * 512 + n0 + tn0 + 4] = *(float4*)&o[4];
        }
    }
}

// GEMM2: Z[rows,40] = H[rows,512] @ W2[512,40] + b2 ; thread-per-row, K chunked by 32
__global__ __launch_bounds__(256) void gemm2(const float* __restrict__ H,
                                             const float* __restrict__ W2,
                                             const float* __restrict__ b2,
                                             float* __restrict__ Z,
                                             int row_start, int row_end) {
    __shared__ float hs[256][33];
    __shared__ float ws2[32][40];
    const int tid = threadIdx.x;
    const int rbase = row_start + blockIdx.x * 256;
    const int r = rbase + tid;
    float acc[40];
    #pragma unroll
    for (int c = 0; c < 40; ++c) acc[c] = b2[c];

    for (int kb = 0; kb < 512; kb += 32) {
        #pragma unroll
        for (int i = 0; i < 8; ++i) {
            int f4 = tid + i * 256;       // 0..2047 float4 id
            int rr = f4 >> 3;
            int kq = f4 & 7;
            int gr = min(rbase + rr, row_end - 1);
            float4 v = *(const float4*)&H[(size_t)(gr - row_start) * 512 + kb + kq * 4];
            hs[rr][kq * 4 + 0] = v.x;
            hs[rr][kq * 4 + 1] = v.y;
            hs[rr][kq * 4 + 2] = v.z;
            hs[rr][kq * 4 + 3] = v.w;
        }
        for (int l = tid; l < 32 * 40; l += 256)
            ws2[l / 40][l % 40] = W2[(size_t)(kb + l / 40) * 40 + (l % 40)];
        __syncthreads();
        #pragma unroll
        for (int kk = 0; kk < 32; ++kk) {
            float hv = hs[tid][kk];
            #pragma unroll
            for (int c4 = 0; c4 < 10; ++c4) {
                float4 w4 = *(const float4*)&ws2[kk][c4 * 4];
                acc[c4 * 4 + 0] = fmaf(hv, w4.x, acc[c4 * 4 + 0]);
                acc[c4 * 4 + 1] = fmaf(hv, w4.y, acc[c4 * 4 + 1]);
                acc[c4 * 4 + 2] = fmaf(hv, w4.z, acc[c4 * 4 + 2]);
                acc[c4 * 4 + 3] = fmaf(hv, w4.w, acc[c4 * 4 + 3]);
            }
        }
        __syncthreads();
    }
    if (r < row_end) {
        #pragma unroll
        for (int c = 0; c < 40; c += 4) {
            float4 v = {acc[c], acc[c + 1], acc[c + 2], acc[c + 3]};
            *(float4*)&Z[(size_t)r * 40 + c] = v;
        }
    }
}

// ---------------- propagation ----------------
// one 64-lane wave per node; lanes 0..39 carry features
__global__ void prop(const float* __restrict__ zin, float* __restrict__ zout,
                     const float* __restrict__ z0, const float* __restrict__ dinv,
                     const int* __restrict__ rp, const int* __restrict__ cols,
                     const float* __restrict__ wst) {
    int wid = (blockIdx.x * blockDim.x + threadIdx.x) >> 6;
    int lane = threadIdx.x & 63;
    if (wid >= NN) return;
    int start = rp[wid], end = rp[wid + 1];
    float d = dinv[wid];
    float acc = 0.0f;
    if (lane < 40) acc = d * d * zin[(size_t)wid * 40 + lane];
    for (int p = start; p < end; ++p) {
        int c = cols[p];
        float we = wst[p];
        if (lane < 40) acc += we * zin[(size_t)c * 40 + lane];
    }
    if (lane < 40)
        zout[(size_t)wid * 40 + lane] = 0.9f * acc + 0.1f * z0[(size_t)wid * 40 + lane];
}

// ---------------- launch ----------------

extern "C" void kernel_launch(void* const* d_in, const int* in_sizes, int n_in,
                              void* d_out, int out_size, void* d_ws, size_t ws_size,
                              hipStream_t stream) {
    const float* x  = (const float*)d_in[0];
    const float* W1 = (const float*)d_in[1];
    const float* b1 = (const float*)d_in[2];
    const float* W2 = (const float*)d_in[3];
    const float* b2 = (const float*)d_in[4];
    const int*   ei = (const int*)d_in[5];
    const int* erow = ei;          // targets
    const int* ecol = ei + NE;     // sources
    float* out = (float*)d_out;

    const int CH = 25600;  // GEMM row-chunk

    char* p = (char*)d_ws;
    auto alloc = [&](size_t bytes) { char* q = p; p += (bytes + 255) & ~(size_t)255; return q; };
    float* h    = (float*)alloc((size_t)CH * 512 * 4);
    float* z0   = (float*)alloc((size_t)NN * 40 * 4);
    float* zA   = (float*)alloc((size_t)NN * 40 * 4);
    float* zB   = (float*)alloc((size_t)NN * 40 * 4);
    float* dinv = (float*)alloc((size_t)NN * 4);
    int* degc   = (int*)alloc((size_t)NN * 4);
    int* rp     = (int*)alloc((size_t)(NN + 1) * 4);
    int* cur    = (int*)alloc((size_t)NN * 4);
    int* bsums  = (int*)alloc(512 * 4);
    int* cols   = (int*)alloc((size_t)NE * 4);
    float* wst  = (float*)alloc((size_t)NE * 4);

    const int nScanBlocks = (NN + 255) / 256;  // 391

    // graph build
    hipMemsetAsync(degc, 0, (size_t)NN * 4, stream);
    count_edges<<<1024, 256, 0, stream>>>(erow, degc, NE);
    compute_dinv<<<nScanBlocks, 256, 0, stream>>>(degc, dinv, NN);
    scan_block<<<nScanBlocks, 256, 0, stream>>>(degc, rp, bsums, NN);
    scan_small<<<1, 512, 0, stream>>>(bsums, nScanBlocks);
    scan_add<<<nScanBlocks, 256, 0, stream>>>(rp, bsums, cur, NN, NE);
    scatter_edges<<<1024, 256, 0, stream>>>(erow, ecol, dinv, cur, cols, wst, NE);

    // MLP in row chunks (reuse h buffer)
    for (int rs = 0; rs < NN; rs += CH) {
        int re = min(rs + CH, NN);
        int rows = re - rs;
        dim3 g1((512 / 128), (rows + 127) / 128);
        gemm1<<<g1, 256, 0, stream>>>(x, W1, b1, h, rs, re);
        gemm2<<<(rows + 255) / 256, 256, 0, stream>>>(h, W2, b2, z0, rs, re);
    }

    // K=10 propagation, ping-pong, last writes d_out
    const float* zin = z0;
    for (int t = 0; t < KITER; ++t) {
        float* zo = (t == KITER - 1) ? out : ((t & 1) ? zB : zA);
        prop<<<(NN * 64 + 255) / 256, 256, 0, stream>>>(zin, zo, z0, dinv, rp, cols, wst);
        zin = zo;
    }
}

// Round 3
// 2861.866 us; speedup vs baseline: 1.1586x; 1.1586x over previous
//
#include <hip/hip_runtime.h>
#include <hip/hip_bf16.h>

#define NN 100000
#define FIN 512
#define HID 512
#define NC 40
#define NE 1600000
#define KITER 10

typedef __attribute__((ext_vector_type(8))) short short8b;
typedef __attribute__((ext_vector_type(4))) float floatx4;

#define GLD16(gp, lp) __builtin_amdgcn_global_load_lds( \
    (const __attribute__((address_space(1))) void*)(gp), \
    (__attribute__((address_space(3))) void*)(lp), 16, 0, 0)

__device__ __forceinline__ unsigned short f2bf_rn(float f) {
    union { float f; unsigned u; } x; x.f = f;
    unsigned r = x.u + 0x7fffu + ((x.u >> 16) & 1u);
    return (unsigned short)(r >> 16);
}
__device__ __forceinline__ float bf2f(unsigned short h) {
    union { unsigned u; float f; } y; y.u = ((unsigned)h) << 16;
    return y.f;
}

// ---------------- graph build ----------------

__global__ void count_edges(const int* __restrict__ row, int* __restrict__ degc, int e) {
    for (int i = blockIdx.x * blockDim.x + threadIdx.x; i < e; i += gridDim.x * blockDim.x)
        atomicAdd(&degc[row[i]], 1);
}

__global__ void compute_dinv(const int* __restrict__ degc, float* __restrict__ dinv, int n) {
    int g = blockIdx.x * blockDim.x + threadIdx.x;
    if (g < n) dinv[g] = 1.0f / sqrtf((float)(degc[g] + 1));  // +1 self-loop
}

__global__ void scan_block(const int* __restrict__ in, int* __restrict__ outExc,
                           int* __restrict__ bsum, int n) {
    __shared__ int s[256];
    int t = threadIdx.x, g = blockIdx.x * 256 + t;
    int v = (g < n) ? in[g] : 0;
    s[t] = v; __syncthreads();
    for (int off = 1; off < 256; off <<= 1) {
        int x = (t >= off) ? s[t - off] : 0;
        __syncthreads();
        s[t] += x;
        __syncthreads();
    }
    if (g < n) outExc[g] = s[t] - v;
    if (t == 255) bsum[blockIdx.x] = s[255];
}

__global__ void scan_small(int* __restrict__ data, int n) {  // n <= 512, exclusive in-place
    __shared__ int s[512];
    int t = threadIdx.x;
    int v = (t < n) ? data[t] : 0;
    s[t] = v; __syncthreads();
    for (int off = 1; off < 512; off <<= 1) {
        int x = (t >= off) ? s[t - off] : 0;
        __syncthreads();
        s[t] += x;
        __syncthreads();
    }
    if (t < n) data[t] = s[t] - v;
}

__global__ void scan_add(int* __restrict__ rp, const int* __restrict__ bsum,
                         int* __restrict__ cur, int n, int total) {
    int g = blockIdx.x * 256 + threadIdx.x;
    if (g < n) {
        int v = rp[g] + bsum[blockIdx.x];
        rp[g] = v;
        cur[g] = v;
    }
    if (g == 0) rp[n] = total;
}

__global__ void scatter_edges(const int* __restrict__ row, const int* __restrict__ col,
                              const float* __restrict__ dinv, int* __restrict__ cur,
                              int* __restrict__ cols, float* __restrict__ wst, int e) {
    for (int i = blockIdx.x * blockDim.x + threadIdx.x; i < e; i += gridDim.x * blockDim.x) {
        int r = row[i], c = col[i];
        int slot = atomicAdd(&cur[r], 1);
        cols[slot] = c;
        wst[slot] = dinv[r] * dinv[c];
    }
}

// ---------------- precision-split pre-passes ----------------

// x chunk (f32) -> hi/lo bf16, row-major [rows][512]
__global__ void split_x(const float* __restrict__ x, unsigned short* __restrict__ hi,
                        unsigned short* __restrict__ lo, long n4) {
    long i = (long)blockIdx.x * 256 + threadIdx.x;
    if (i >= n4) return;
    float4 v = ((const float4*)x)[i];
    unsigned short h0 = f2bf_rn(v.x), h1 = f2bf_rn(v.y), h2 = f2bf_rn(v.z), h3 = f2bf_rn(v.w);
    ushort4 hv; hv.x = h0; hv.y = h1; hv.z = h2; hv.w = h3;
    ((ushort4*)hi)[i] = hv;
    ushort4 lv;
    lv.x = f2bf_rn(v.x - bf2f(h0));
    lv.y = f2bf_rn(v.y - bf2f(h1));
    lv.z = f2bf_rn(v.z - bf2f(h2));
    lv.w = f2bf_rn(v.w - bf2f(h3));
    ((ushort4*)lo)[i] = lv;
}

// W1 [K=512][N=512] f32 -> transposed hi/lo bf16 [N][K]
__global__ void split_w1t(const float* __restrict__ W1, unsigned short* __restrict__ hi,
                          unsigned short* __restrict__ lo) {
    int idx = blockIdx.x * 256 + threadIdx.x;  // 0 .. 512*512-1
    int k = idx >> 9, n = idx & 511;
    float w = W1[idx];
    unsigned short h = f2bf_rn(w);
    hi[(size_t)n * 512 + k] = h;
    lo[(size_t)n * 512 + k] = f2bf_rn(w - bf2f(h));
}

// ---------------- GEMM1 via MFMA (split-bf16, 3 terms) ----------------
// H[rows,512] = relu( (Ahi+Alo) @ (W1hi+W1lo) + b1 ), B given transposed [N][K].
// 128x128 tile, BK=32, 4 waves (2x2), each wave 64x64 = 4x4 frags of 16x16x32.
__global__ __launch_bounds__(256) void gemm1_mfma(
    const unsigned short* __restrict__ Ahi, const unsigned short* __restrict__ Alo,
    const unsigned short* __restrict__ Bhi, const unsigned short* __restrict__ Blo,
    const float* __restrict__ b1, float* __restrict__ H, int rows_c) {
    __shared__ char smem[32768];  // Ahi 0, Alo 8192, Bhi 16384, Blo 24576 (each 128x32 bf16)
    const int tid = threadIdx.x;
    const int lane = tid & 63, wid = tid >> 6;
    const int wr = wid >> 1, wc = wid & 1;
    const int fr = lane & 15, kb = lane >> 4;
    const int bx = blockIdx.x, by = blockIdx.y;

    // staging geometry: thread covers bytes off0/off1 of each 8192B tile (linear lane order)
    const int segbase = wid * 1024;
    const int off0 = segbase + (lane << 4);
    const int off1 = off0 + 4096;
    const int row0 = off0 >> 6, slot0 = (off0 >> 4) & 3;
    const int row1 = off1 >> 6, slot1 = (off1 >> 4) & 3;
    const int ss0 = slot0 ^ ((row0 >> 1) & 3);  // pre-swizzled source slot (T2/m173 pattern)
    const int ss1 = slot1 ^ ((row1 >> 1) & 3);
    const int ar0 = min(by * 128 + row0, rows_c - 1);
    const int ar1 = min(by * 128 + row1, rows_c - 1);
    const int br0 = bx * 128 + row0;
    const int br1 = bx * 128 + row1;

    const unsigned short* pAh0 = Ahi + (size_t)ar0 * 512 + ss0 * 8;
    const unsigned short* pAh1 = Ahi + (size_t)ar1 * 512 + ss1 * 8;
    const unsigned short* pAl0 = Alo + (size_t)ar0 * 512 + ss0 * 8;
    const unsigned short* pAl1 = Alo + (size_t)ar1 * 512 + ss1 * 8;
    const unsigned short* pBh0 = Bhi + (size_t)br0 * 512 + ss0 * 8;
    const unsigned short* pBh1 = Bhi + (size_t)br1 * 512 + ss1 * 8;
    const unsigned short* pBl0 = Blo + (size_t)br0 * 512 + ss0 * 8;
    const unsigned short* pBl1 = Blo + (size_t)br1 * 512 + ss1 * 8;

    char* dst0 = smem + segbase;          // +tile offset, +4096 for seg1
    floatx4 acc[4][4] = {};

    for (int ks = 0; ks < 16; ++ks) {
        GLD16(pAh0, dst0);
        GLD16(pAh1, dst0 + 4096);
        GLD16(pAl0, dst0 + 8192);
        GLD16(pAl1, dst0 + 8192 + 4096);
        GLD16(pBh0, dst0 + 16384);
        GLD16(pBh1, dst0 + 16384 + 4096);
        GLD16(pBl0, dst0 + 24576);
        GLD16(pBl1, dst0 + 24576 + 4096);
        pAh0 += 32; pAh1 += 32; pAl0 += 32; pAl1 += 32;
        pBh0 += 32; pBh1 += 32; pBl0 += 32; pBl1 += 32;
        __syncthreads();  // drains vmcnt -> staged data visible

        short8b ah[4], al[4], bh[4], bl[4];
        #pragma unroll
        for (int m = 0; m < 4; ++m) {
            int rrow = wr * 64 + m * 16 + fr;
            int adr = rrow * 64 + ((kb ^ ((rrow >> 1) & 3)) << 4);
            ah[m] = *(const short8b*)(smem + adr);
            al[m] = *(const short8b*)(smem + 8192 + adr);
        }
        #pragma unroll
        for (int n = 0; n < 4; ++n) {
            int rrow = wc * 64 + n * 16 + fr;
            int adr = rrow * 64 + ((kb ^ ((rrow >> 1) & 3)) << 4);
            bh[n] = *(const short8b*)(smem + 16384 + adr);
            bl[n] = *(const short8b*)(smem + 24576 + adr);
        }
        #pragma unroll
        for (int m = 0; m < 4; ++m)
            #pragma unroll
            for (int n = 0; n < 4; ++n) {
                acc[m][n] = __builtin_amdgcn_mfma_f32_16x16x32_bf16(al[m], bh[n], acc[m][n], 0, 0, 0);
                acc[m][n] = __builtin_amdgcn_mfma_f32_16x16x32_bf16(ah[m], bl[n], acc[m][n], 0, 0, 0);
                acc[m][n] = __builtin_amdgcn_mfma_f32_16x16x32_bf16(ah[m], bh[n], acc[m][n], 0, 0, 0);
            }
        __syncthreads();  // protect LDS before next stage
    }

    // epilogue: C/D layout col=lane&15, row=(lane>>4)*4+reg  [m89]
    #pragma unroll
    for (int m = 0; m < 4; ++m) {
        int rbase = by * 128 + wr * 64 + m * 16 + kb * 4;
        #pragma unroll
        for (int n = 0; n < 4; ++n) {
            int c = bx * 128 + wc * 64 + n * 16 + fr;
            float bv = b1[c];
            #pragma unroll
            for (int q = 0; q < 4; ++q) {
                int rr = rbase + q;
                if (rr < rows_c)
                    H[(size_t)rr * 512 + c] = fmaxf(acc[m][n][q] + bv, 0.0f);
            }
        }
    }
}

// GEMM2: Z[rows,40] = H[rows,512] @ W2[512,40] + b2 ; thread-per-row, K chunked by 32
__global__ __launch_bounds__(256) void gemm2(const float* __restrict__ H,
                                             const float* __restrict__ W2,
                                             const float* __restrict__ b2,
                                             float* __restrict__ Z,
                                             int row_start, int row_end) {
    __shared__ float hs[256][33];
    __shared__ float ws2[32][40];
    const int tid = threadIdx.x;
    const int rbase = row_start + blockIdx.x * 256;
    const int r = rbase + tid;
    float acc[40];
    #pragma unroll
    for (int c = 0; c < 40; ++c) acc[c] = b2[c];

    for (int kb = 0; kb < 512; kb += 32) {
        #pragma unroll
        for (int i = 0; i < 8; ++i) {
            int f4 = tid + i * 256;
            int rr = f4 >> 3;
            int kq = f4 & 7;
            int gr = min(rbase + rr, row_end - 1);
            float4 v = *(const float4*)&H[(size_t)(gr - row_start) * 512 + kb + kq * 4];
            hs[rr][kq * 4 + 0] = v.x;
            hs[rr][kq * 4 + 1] = v.y;
            hs[rr][kq * 4 + 2] = v.z;
            hs[rr][kq * 4 + 3] = v.w;
        }
        for (int l = tid; l < 32 * 40; l += 256)
            ws2[l / 40][l % 40] = W2[(size_t)(kb + l / 40) * 40 + (l % 40)];
        __syncthreads();
        #pragma unroll
        for (int kk = 0; kk < 32; ++kk) {
            float hv = hs[tid][kk];
            #pragma unroll
            for (int c4 = 0; c4 < 10; ++c4) {
                float4 w4 = *(const float4*)&ws2[kk][c4 * 4];
                acc[c4 * 4 + 0] = fmaf(hv, w4.x, acc[c4 * 4 + 0]);
                acc[c4 * 4 + 1] = fmaf(hv, w4.y, acc[c4 * 4 + 1]);
                acc[c4 * 4 + 2] = fmaf(hv, w4.z, acc[c4 * 4 + 2]);
                acc[c4 * 4 + 3] = fmaf(hv, w4.w, acc[c4 * 4 + 3]);
            }
        }
        __syncthreads();
    }
    if (r < row_end) {
        #pragma unroll
        for (int c = 0; c < 40; c += 4) {
            float4 v = {acc[c], acc[c + 1], acc[c + 2], acc[c + 3]};
            *(float4*)&Z[(size_t)r * 40 + c] = v;
        }
    }
}

// ---------------- propagation ----------------
__global__ void prop(const float* __restrict__ zin, float* __restrict__ zout,
                     const float* __restrict__ z0, const float* __restrict__ dinv,
                     const int* __restrict__ rp, const int* __restrict__ cols,
                     const float* __restrict__ wst) {
    int wid = (blockIdx.x * blockDim.x + threadIdx.x) >> 6;
    int lane = threadIdx.x & 63;
    if (wid >= NN) return;
    int start = rp[wid], end = rp[wid + 1];
    float d = dinv[wid];
    float acc = 0.0f;
    if (lane < 40) acc = d * d * zin[(size_t)wid * 40 + lane];
    for (int p = start; p < end; ++p) {
        int c = cols[p];
        float we = wst[p];
        if (lane < 40) acc += we * zin[(size_t)c * 40 + lane];
    }
    if (lane < 40)
        zout[(size_t)wid * 40 + lane] = 0.9f * acc + 0.1f * z0[(size_t)wid * 40 + lane];
}

// ---------------- launch ----------------

extern "C" void kernel_launch(void* const* d_in, const int* in_sizes, int n_in,
                              void* d_out, int out_size, void* d_ws, size_t ws_size,
                              hipStream_t stream) {
    const float* x  = (const float*)d_in[0];
    const float* W1 = (const float*)d_in[1];
    const float* b1 = (const float*)d_in[2];
    const float* W2 = (const float*)d_in[3];
    const float* b2 = (const float*)d_in[4];
    const int*   ei = (const int*)d_in[5];
    const int* erow = ei;          // targets
    const int* ecol = ei + NE;     // sources
    float* out = (float*)d_out;

    char* p = (char*)d_ws;
    auto alloc = [&](size_t bytes) { char* q = p; p += (bytes + 255) & ~(size_t)255; return q; };
    // fixed allocations first
    float* z0   = (float*)alloc((size_t)NN * 40 * 4);
    float* zA   = (float*)alloc((size_t)NN * 40 * 4);
    float* zB   = (float*)alloc((size_t)NN * 40 * 4);
    float* dinv = (float*)alloc((size_t)NN * 4);
    int* degc   = (int*)alloc((size_t)NN * 4);
    int* rp     = (int*)alloc((size_t)(NN + 1) * 4);
    int* cur    = (int*)alloc((size_t)NN * 4);
    int* bsums  = (int*)alloc(512 * 4);
    int* cols   = (int*)alloc((size_t)NE * 4);
    float* wst  = (float*)alloc((size_t)NE * 4);
    unsigned short* w1thi = (unsigned short*)alloc((size_t)512 * 512 * 2);
    unsigned short* w1tlo = (unsigned short*)alloc((size_t)512 * 512 * 2);

    // chunk region sized by remaining workspace: per row 512*(2+2+4) = 4096 B
    size_t used = (size_t)(p - (char*)d_ws);
    size_t remain = (ws_size > used) ? (ws_size - used - 1024) : 0;
    int CH = (int)((remain / 4096) & ~(size_t)127);
    if (CH > 25600) CH = 25600;
    if (CH < 128) CH = 128;  // assume ws is at least this generous
    unsigned short* xhi_c = (unsigned short*)alloc((size_t)CH * 512 * 2);
    unsigned short* xlo_c = (unsigned short*)alloc((size_t)CH * 512 * 2);
    float* h = (float*)alloc((size_t)CH * 512 * 4);

    const int nScanBlocks = (NN + 255) / 256;  // 391

    // graph build
    hipMemsetAsync(degc, 0, (size_t)NN * 4, stream);
    count_edges<<<1024, 256, 0, stream>>>(erow, degc, NE);
    compute_dinv<<<nScanBlocks, 256, 0, stream>>>(degc, dinv, NN);
    scan_block<<<nScanBlocks, 256, 0, stream>>>(degc, rp, bsums, NN);
    scan_small<<<1, 512, 0, stream>>>(bsums, nScanBlocks);
    scan_add<<<nScanBlocks, 256, 0, stream>>>(rp, bsums, cur, NN, NE);
    scatter_edges<<<1024, 256, 0, stream>>>(erow, ecol, dinv, cur, cols, wst, NE);

    // W1 transpose + hi/lo split (once)
    split_w1t<<<(512 * 512) / 256, 256, 0, stream>>>(W1, w1thi, w1tlo);

    // MLP in row chunks
    for (int rs = 0; rs < NN; rs += CH) {
        int re = min(rs + CH, NN);
        int rows = re - rs;
        long n4 = (long)rows * 128;  // float4 count
        split_x<<<(int)((n4 + 255) / 256), 256, 0, stream>>>(x + (size_t)rs * 512, xhi_c, xlo_c, n4);
        dim3 g1(4, (rows + 127) / 128);
        gemm1_mfma<<<g1, 256, 0, stream>>>(xhi_c, xlo_c, w1thi, w1tlo, b1, h, rows);
        gemm2<<<(rows + 255) / 256, 256, 0, stream>>>(h, W2, b2, z0, rs, re);
    }

    // K=10 propagation, ping-pong, last writes d_out
    const float* zin = z0;
    for (int t = 0; t < KITER; ++t) {
        float* zo = (t == KITER - 1) ? out : ((t & 1) ? zB : zA);
        prop<<<(NN * 64 + 255) / 256, 256, 0, stream>>>(zin, zo, z0, dinv, rp, cols, wst);
        zin = zo;
    }
}

// Round 5
// 1930.659 us; speedup vs baseline: 1.7174x; 1.4823x over previous
//
#include <hip/hip_runtime.h>
#include <hip/hip_bf16.h>

#define NN 100000
#define FIN 512
#define HID 512
#define NC 40
#define NE 1600000
#define KITER 10

typedef __attribute__((ext_vector_type(8))) short short8b;
typedef __attribute__((ext_vector_type(4))) float floatx4;

#define GLD16(gp, lp) __builtin_amdgcn_global_load_lds( \
    (const __attribute__((address_space(1))) void*)(gp), \
    (__attribute__((address_space(3))) void*)(lp), 16, 0, 0)

__device__ __forceinline__ unsigned short f2bf_rn(float f) {
    union { float f; unsigned u; } x; x.f = f;
    unsigned r = x.u + 0x7fffu + ((x.u >> 16) & 1u);
    return (unsigned short)(r >> 16);
}
__device__ __forceinline__ float bf2f(unsigned short h) {
    union { unsigned u; float f; } y; y.u = ((unsigned)h) << 16;
    return y.f;
}

// ---------------- graph build ----------------

__global__ void count_edges(const int* __restrict__ row, int* __restrict__ degc, int e) {
    for (int i = blockIdx.x * blockDim.x + threadIdx.x; i < e; i += gridDim.x * blockDim.x)
        atomicAdd(&degc[row[i]], 1);
}

__global__ void compute_dinv(const int* __restrict__ degc, float* __restrict__ dinv, int n) {
    int g = blockIdx.x * blockDim.x + threadIdx.x;
    if (g < n) dinv[g] = 1.0f / sqrtf((float)(degc[g] + 1));  // +1 self-loop
}

__global__ void scan_block(const int* __restrict__ in, int* __restrict__ outExc,
                           int* __restrict__ bsum, int n) {
    __shared__ int s[256];
    int t = threadIdx.x, g = blockIdx.x * 256 + t;
    int v = (g < n) ? in[g] : 0;
    s[t] = v; __syncthreads();
    for (int off = 1; off < 256; off <<= 1) {
        int x = (t >= off) ? s[t - off] : 0;
        __syncthreads();
        s[t] += x;
        __syncthreads();
    }
    if (g < n) outExc[g] = s[t] - v;
    if (t == 255) bsum[blockIdx.x] = s[255];
}

__global__ void scan_small(int* __restrict__ data, int n) {  // n <= 512, exclusive in-place
    __shared__ int s[512];
    int t = threadIdx.x;
    int v = (t < n) ? data[t] : 0;
    s[t] = v; __syncthreads();
    for (int off = 1; off < 512; off <<= 1) {
        int x = (t >= off) ? s[t - off] : 0;
        __syncthreads();
        s[t] += x;
        __syncthreads();
    }
    if (t < n) data[t] = s[t] - v;
}

__global__ void scan_add(int* __restrict__ rp, const int* __restrict__ bsum,
                         int* __restrict__ cur, int n, int total) {
    int g = blockIdx.x * 256 + threadIdx.x;
    if (g < n) {
        int v = rp[g] + bsum[blockIdx.x];
        rp[g] = v;
        cur[g] = v;
    }
    if (g == 0) rp[n] = total;
}

__global__ void scatter_edges(const int* __restrict__ row, const int* __restrict__ col,
                              const float* __restrict__ dinv, int* __restrict__ cur,
                              int* __restrict__ cols, float* __restrict__ wst, int e) {
    for (int i = blockIdx.x * blockDim.x + threadIdx.x; i < e; i += gridDim.x * blockDim.x) {
        int r = row[i], c = col[i];
        int slot = atomicAdd(&cur[r], 1);
        cols[slot] = c;
        wst[slot] = dinv[r] * dinv[c];
    }
}

// ---------------- precision-split pre-passes ----------------

__global__ void split_x(const float* __restrict__ x, unsigned short* __restrict__ hi,
                        unsigned short* __restrict__ lo, long n4) {
    long i = (long)blockIdx.x * 256 + threadIdx.x;
    if (i >= n4) return;
    float4 v = ((const float4*)x)[i];
    unsigned short h0 = f2bf_rn(v.x), h1 = f2bf_rn(v.y), h2 = f2bf_rn(v.z), h3 = f2bf_rn(v.w);
    ushort4 hv; hv.x = h0; hv.y = h1; hv.z = h2; hv.w = h3;
    ((ushort4*)hi)[i] = hv;
    ushort4 lv;
    lv.x = f2bf_rn(v.x - bf2f(h0));
    lv.y = f2bf_rn(v.y - bf2f(h1));
    lv.z = f2bf_rn(v.z - bf2f(h2));
    lv.w = f2bf_rn(v.w - bf2f(h3));
    ((ushort4*)lo)[i] = lv;
}

__global__ void split_w1t(const float* __restrict__ W1, unsigned short* __restrict__ hi,
                          unsigned short* __restrict__ lo) {
    int idx = blockIdx.x * 256 + threadIdx.x;  // 0 .. 512*512-1
    int k = idx >> 9, n = idx & 511;
    float w = W1[idx];
    unsigned short h = f2bf_rn(w);
    hi[(size_t)n * 512 + k] = h;
    lo[(size_t)n * 512 + k] = f2bf_rn(w - bf2f(h));
}

// ---------------- GEMM1 via MFMA (split-bf16, 3 terms) ----------------
__global__ __launch_bounds__(256) void gemm1_mfma(
    const unsigned short* __restrict__ Ahi, const unsigned short* __restrict__ Alo,
    const unsigned short* __restrict__ Bhi, const unsigned short* __restrict__ Blo,
    const float* __restrict__ b1, float* __restrict__ H, int rows_c) {
    __shared__ char smem[32768];  // Ahi 0, Alo 8192, Bhi 16384, Blo 24576 (each 128x32 bf16)
    const int tid = threadIdx.x;
    const int lane = tid & 63, wid = tid >> 6;
    const int wr = wid >> 1, wc = wid & 1;
    const int fr = lane & 15, kb = lane >> 4;
    const int bx = blockIdx.x, by = blockIdx.y;

    const int segbase = wid * 1024;
    const int off0 = segbase + (lane << 4);
    const int off1 = off0 + 4096;
    const int row0 = off0 >> 6, slot0 = (off0 >> 4) & 3;
    const int row1 = off1 >> 6, slot1 = (off1 >> 4) & 3;
    const int ss0 = slot0 ^ ((row0 >> 1) & 3);
    const int ss1 = slot1 ^ ((row1 >> 1) & 3);
    const int ar0 = min(by * 128 + row0, rows_c - 1);
    const int ar1 = min(by * 128 + row1, rows_c - 1);
    const int br0 = bx * 128 + row0;
    const int br1 = bx * 128 + row1;

    const unsigned short* pAh0 = Ahi + (size_t)ar0 * 512 + ss0 * 8;
    const unsigned short* pAh1 = Ahi + (size_t)ar1 * 512 + ss1 * 8;
    const unsigned short* pAl0 = Alo + (size_t)ar0 * 512 + ss0 * 8;
    const unsigned short* pAl1 = Alo + (size_t)ar1 * 512 + ss1 * 8;
    const unsigned short* pBh0 = Bhi + (size_t)br0 * 512 + ss0 * 8;
    const unsigned short* pBh1 = Bhi + (size_t)br1 * 512 + ss1 * 8;
    const unsigned short* pBl0 = Blo + (size_t)br0 * 512 + ss0 * 8;
    const unsigned short* pBl1 = Blo + (size_t)br1 * 512 + ss1 * 8;

    char* dst0 = smem + segbase;
    floatx4 acc[4][4] = {};

    for (int ks = 0; ks < 16; ++ks) {
        GLD16(pAh0, dst0);
        GLD16(pAh1, dst0 + 4096);
        GLD16(pAl0, dst0 + 8192);
        GLD16(pAl1, dst0 + 8192 + 4096);
        GLD16(pBh0, dst0 + 16384);
        GLD16(pBh1, dst0 + 16384 + 4096);
        GLD16(pBl0, dst0 + 24576);
        GLD16(pBl1, dst0 + 24576 + 4096);
        pAh0 += 32; pAh1 += 32; pAl0 += 32; pAl1 += 32;
        pBh0 += 32; pBh1 += 32; pBl0 += 32; pBl1 += 32;
        __syncthreads();

        short8b ah[4], al[4], bh[4], bl[4];
        #pragma unroll
        for (int m = 0; m < 4; ++m) {
            int rrow = wr * 64 + m * 16 + fr;
            int adr = rrow * 64 + ((kb ^ ((rrow >> 1) & 3)) << 4);
            ah[m] = *(const short8b*)(smem + adr);
            al[m] = *(const short8b*)(smem + 8192 + adr);
        }
        #pragma unroll
        for (int n = 0; n < 4; ++n) {
            int rrow = wc * 64 + n * 16 + fr;
            int adr = rrow * 64 + ((kb ^ ((rrow >> 1) & 3)) << 4);
            bh[n] = *(const short8b*)(smem + 16384 + adr);
            bl[n] = *(const short8b*)(smem + 24576 + adr);
        }
        #pragma unroll
        for (int m = 0; m < 4; ++m)
            #pragma unroll
            for (int n = 0; n < 4; ++n) {
                acc[m][n] = __builtin_amdgcn_mfma_f32_16x16x32_bf16(al[m], bh[n], acc[m][n], 0, 0, 0);
                acc[m][n] = __builtin_amdgcn_mfma_f32_16x16x32_bf16(ah[m], bl[n], acc[m][n], 0, 0, 0);
                acc[m][n] = __builtin_amdgcn_mfma_f32_16x16x32_bf16(ah[m], bh[n], acc[m][n], 0, 0, 0);
            }
        __syncthreads();
    }

    #pragma unroll
    for (int m = 0; m < 4; ++m) {
        int rbase = by * 128 + wr * 64 + m * 16 + kb * 4;
        #pragma unroll
        for (int n = 0; n < 4; ++n) {
            int c = bx * 128 + wc * 64 + n * 16 + fr;
            float bv = b1[c];
            #pragma unroll
            for (int q = 0; q < 4; ++q) {
                int rr = rbase + q;
                if (rr < rows_c)
                    H[(size_t)rr * 512 + c] = fmaxf(acc[m][n][q] + bv, 0.0f);
            }
        }
    }
}

// GEMM2: Z[rows,40] = H[rows,512] @ W2[512,40] + b2
__global__ __launch_bounds__(256) void gemm2(const float* __restrict__ H,
                                             const float* __restrict__ W2,
                                             const float* __restrict__ b2,
                                             float* __restrict__ Z,
                                             int row_start, int row_end) {
    __shared__ float hs[256][33];
    __shared__ float ws2[32][40];
    const int tid = threadIdx.x;
    const int rbase = row_start + blockIdx.x * 256;
    const int r = rbase + tid;
    float acc[40];
    #pragma unroll
    for (int c = 0; c < 40; ++c) acc[c] = b2[c];

    for (int kb = 0; kb < 512; kb += 32) {
        #pragma unroll
        for (int i = 0; i < 8; ++i) {
            int f4 = tid + i * 256;
            int rr = f4 >> 3;
            int kq = f4 & 7;
            int gr = min(rbase + rr, row_end - 1);
            float4 v = *(const float4*)&H[(size_t)(gr - row_start) * 512 + kb + kq * 4];
            hs[rr][kq * 4 + 0] = v.x;
            hs[rr][kq * 4 + 1] = v.y;
            hs[rr][kq * 4 + 2] = v.z;
            hs[rr][kq * 4 + 3] = v.w;
        }
        for (int l = tid; l < 32 * 40; l += 256)
            ws2[l / 40][l % 40] = W2[(size_t)(kb + l / 40) * 40 + (l % 40)];
        __syncthreads();
        #pragma unroll
        for (int kk = 0; kk < 32; ++kk) {
            float hv = hs[tid][kk];
            #pragma unroll
            for (int c4 = 0; c4 < 10; ++c4) {
                float4 w4 = *(const float4*)&ws2[kk][c4 * 4];
                acc[c4 * 4 + 0] = fmaf(hv, w4.x, acc[c4 * 4 + 0]);
                acc[c4 * 4 + 1] = fmaf(hv, w4.y, acc[c4 * 4 + 1]);
                acc[c4 * 4 + 2] = fmaf(hv, w4.z, acc[c4 * 4 + 2]);
                acc[c4 * 4 + 3] = fmaf(hv, w4.w, acc[c4 * 4 + 3]);
            }
        }
        __syncthreads();
    }
    if (r < row_end) {
        #pragma unroll
        for (int c = 0; c < 40; c += 4) {
            float4 v = {acc[c], acc[c + 1], acc[c + 2], acc[c + 3]};
            *(float4*)&Z[(size_t)r * 40 + c] = v;
        }
    }
}

// ---------------- propagation ----------------
// one wave per node; lanes 0..39 = features; edge loop unrolled 8/4/1 so
// 8 independent gathers are in flight per wave (MLP fix for latency-bound prop).
// fmaf order matches the sequential p-order -> deterministic, same rounding.
__global__ __launch_bounds__(256) void prop(const float* __restrict__ zin,
                                            float* __restrict__ zout,
                                            const float* __restrict__ z0,
                                            const float* __restrict__ dinv,
                                            const int* __restrict__ rp,
                                            const int* __restrict__ cols,
                                            const float* __restrict__ wst) {
    int wid = (blockIdx.x * blockDim.x + threadIdx.x) >> 6;
    int lane = threadIdx.x & 63;
    if (wid >= NN || lane >= 40) return;
    const int start = rp[wid], end = rp[wid + 1];
    const float d = dinv[wid];
    const size_t fl = lane;
    float acc = d * d * zin[(size_t)wid * 40 + fl];
    int p = start;
    for (; p + 8 <= end; p += 8) {
        int c0 = cols[p + 0], c1 = cols[p + 1], c2 = cols[p + 2], c3 = cols[p + 3];
        int c4 = cols[p + 4], c5 = cols[p + 5], c6 = cols[p + 6], c7 = cols[p + 7];
        float w0 = wst[p + 0], w1 = wst[p + 1], w2 = wst[p + 2], w3 = wst[p + 3];
        float w4 = wst[p + 4], w5 = wst[p + 5], w6 = wst[p + 6], w7 = wst[p + 7];
        float v0 = zin[(size_t)c0 * 40 + fl];
        float v1 = zin[(size_t)c1 * 40 + fl];
        float v2 = zin[(size_t)c2 * 40 + fl];
        float v3 = zin[(size_t)c3 * 40 + fl];
        float v4 = zin[(size_t)c4 * 40 + fl];
        float v5 = zin[(size_t)c5 * 40 + fl];
        float v6 = zin[(size_t)c6 * 40 + fl];
        float v7 = zin[(size_t)c7 * 40 + fl];
        acc = fmaf(w0, v0, acc); acc = fmaf(w1, v1, acc);
        acc = fmaf(w2, v2, acc); acc = fmaf(w3, v3, acc);
        acc = fmaf(w4, v4, acc); acc = fmaf(w5, v5, acc);
        acc = fmaf(w6, v6, acc); acc = fmaf(w7, v7, acc);
    }
    for (; p + 4 <= end; p += 4) {
        int c0 = cols[p + 0], c1 = cols[p + 1], c2 = cols[p + 2], c3 = cols[p + 3];
        float w0 = wst[p + 0], w1 = wst[p + 1], w2 = wst[p + 2], w3 = wst[p + 3];
        float v0 = zin[(size_t)c0 * 40 + fl];
        float v1 = zin[(size_t)c1 * 40 + fl];
        float v2 = zin[(size_t)c2 * 40 + fl];
        float v3 = zin[(size_t)c3 * 40 + fl];
        acc = fmaf(w0, v0, acc); acc = fmaf(w1, v1, acc);
        acc = fmaf(w2, v2, acc); acc = fmaf(w3, v3, acc);
    }
    for (; p < end; ++p)
        acc = fmaf(wst[p], zin[(size_t)cols[p] * 40 + fl], acc);
    zout[(size_t)wid * 40 + fl] = 0.9f * acc + 0.1f * z0[(size_t)wid * 40 + fl];
}

// ---------------- launch ----------------

extern "C" void kernel_launch(void* const* d_in, const int* in_sizes, int n_in,
                              void* d_out, int out_size, void* d_ws, size_t ws_size,
                              hipStream_t stream) {
    const float* x  = (const float*)d_in[0];
    const float* W1 = (const float*)d_in[1];
    const float* b1 = (const float*)d_in[2];
    const float* W2 = (const float*)d_in[3];
    const float* b2 = (const float*)d_in[4];
    const int*   ei = (const int*)d_in[5];
    const int* erow = ei;          // targets
    const int* ecol = ei + NE;     // sources
    float* out = (float*)d_out;

    char* p = (char*)d_ws;
    auto alloc = [&](size_t bytes) { char* q = p; p += (bytes + 255) & ~(size_t)255; return q; };
    float* z0   = (float*)alloc((size_t)NN * 40 * 4);
    float* zA   = (float*)alloc((size_t)NN * 40 * 4);
    float* zB   = (float*)alloc((size_t)NN * 40 * 4);
    float* dinv = (float*)alloc((size_t)NN * 4);
    int* degc   = (int*)alloc((size_t)NN * 4);
    int* rp     = (int*)alloc((size_t)(NN + 1) * 4);
    int* cur    = (int*)alloc((size_t)NN * 4);
    int* bsums  = (int*)alloc(512 * 4);
    int* cols   = (int*)alloc((size_t)NE * 4);
    float* wst  = (float*)alloc((size_t)NE * 4);
    unsigned short* w1thi = (unsigned short*)alloc((size_t)512 * 512 * 2);
    unsigned short* w1tlo = (unsigned short*)alloc((size_t)512 * 512 * 2);

    size_t used = (size_t)(p - (char*)d_ws);
    size_t remain = (ws_size > used) ? (ws_size - used - 1024) : 0;
    int CH = (int)((remain / 4096) & ~(size_t)127);
    if (CH > 25600) CH = 25600;
    if (CH < 128) CH = 128;
    unsigned short* xhi_c = (unsigned short*)alloc((size_t)CH * 512 * 2);
    unsigned short* xlo_c = (unsigned short*)alloc((size_t)CH * 512 * 2);
    float* h = (float*)alloc((size_t)CH * 512 * 4);

    const int nScanBlocks = (NN + 255) / 256;  // 391

    // graph build
    hipMemsetAsync(degc, 0, (size_t)NN * 4, stream);
    count_edges<<<1024, 256, 0, stream>>>(erow, degc, NE);
    compute_dinv<<<nScanBlocks, 256, 0, stream>>>(degc, dinv, NN);
    scan_block<<<nScanBlocks, 256, 0, stream>>>(degc, rp, bsums, NN);
    scan_small<<<1, 512, 0, stream>>>(bsums, nScanBlocks);
    scan_add<<<nScanBlocks, 256, 0, stream>>>(rp, bsums, cur, NN, NE);
    scatter_edges<<<1024, 256, 0, stream>>>(erow, ecol, dinv, cur, cols, wst, NE);

    // W1 transpose + hi/lo split (once)
    split_w1t<<<(512 * 512) / 256, 256, 0, stream>>>(W1, w1thi, w1tlo);

    // MLP in row chunks
    for (int rs = 0; rs < NN; rs += CH) {
        int re = min(rs + CH, NN);
        int rows = re - rs;
        long n4 = (long)rows * 128;
        split_x<<<(int)((n4 + 255) / 256), 256, 0, stream>>>(x + (size_t)rs * 512, xhi_c, xlo_c, n4);
        dim3 g1(4, (rows + 127) / 128);
        gemm1_mfma<<<g1, 256, 0, stream>>>(xhi_c, xlo_c, w1thi, w1tlo, b1, h, rows);
        gemm2<<<(rows + 255) / 256, 256, 0, stream>>>(h, W2, b2, z0, rs, re);
    }

    // K=10 propagation, ping-pong, last writes d_out
    const float* zin = z0;
    for (int t = 0; t < KITER; ++t) {
        float* zo = (t == KITER - 1) ? out : ((t & 1) ? zB : zA);
        prop<<<(NN * 64 + 255) / 256, 256, 0, stream>>>(zin, zo, z0, dinv, rp, cols, wst);
        zin = zo;
    }
}

// Round 7
// 1461.812 us; speedup vs baseline: 2.2682x; 1.3207x over previous
//
#include <hip/hip_runtime.h>
#include <hip/hip_bf16.h>

#define NN 100000
#define FIN 512
#define HID 512
#define NC 40
#define NE 1600000
#define KITER 10

typedef __attribute__((ext_vector_type(8))) short short8b;
typedef __attribute__((ext_vector_type(4))) float floatx4;

#define GLD16(gp, lp) __builtin_amdgcn_global_load_lds( \
    (const __attribute__((address_space(1))) void*)(gp), \
    (__attribute__((address_space(3))) void*)(lp), 16, 0, 0)

__device__ __forceinline__ unsigned short f2bf_rn(float f) {
    union { float f; unsigned u; } x; x.f = f;
    unsigned r = x.u + 0x7fffu + ((x.u >> 16) & 1u);
    return (unsigned short)(r >> 16);
}
__device__ __forceinline__ float bf2f(unsigned short h) {
    union { unsigned u; float f; } y; y.u = ((unsigned)h) << 16;
    return y.f;
}

// ---------------- graph build ----------------

__global__ void count_edges(const int* __restrict__ row, int* __restrict__ degc, int e) {
    for (int i = blockIdx.x * blockDim.x + threadIdx.x; i < e; i += gridDim.x * blockDim.x)
        atomicAdd(&degc[row[i]], 1);
}

__global__ void compute_dinv(const int* __restrict__ degc, float* __restrict__ dinv, int n) {
    int g = blockIdx.x * blockDim.x + threadIdx.x;
    if (g < n) dinv[g] = 1.0f / sqrtf((float)(degc[g] + 1));  // +1 self-loop
}

__global__ void scan_block(const int* __restrict__ in, int* __restrict__ outExc,
                           int* __restrict__ bsum, int n) {
    __shared__ int s[256];
    int t = threadIdx.x, g = blockIdx.x * 256 + t;
    int v = (g < n) ? in[g] : 0;
    s[t] = v; __syncthreads();
    for (int off = 1; off < 256; off <<= 1) {
        int x = (t >= off) ? s[t - off] : 0;
        __syncthreads();
        s[t] += x;
        __syncthreads();
    }
    if (g < n) outExc[g] = s[t] - v;
    if (t == 255) bsum[blockIdx.x] = s[255];
}

__global__ void scan_small(int* __restrict__ data, int n) {  // n <= 512, exclusive in-place
    __shared__ int s[512];
    int t = threadIdx.x;
    int v = (t < n) ? data[t] : 0;
    s[t] = v; __syncthreads();
    for (int off = 1; off < 512; off <<= 1) {
        int x = (t >= off) ? s[t - off] : 0;
        __syncthreads();
        s[t] += x;
        __syncthreads();
    }
    if (t < n) data[t] = s[t] - v;
}

__global__ void scan_add(int* __restrict__ rp, const int* __restrict__ bsum,
                         int* __restrict__ cur, int n, int total) {
    int g = blockIdx.x * 256 + threadIdx.x;
    if (g < n) {
        int v = rp[g] + bsum[blockIdx.x];
        rp[g] = v;
        cur[g] = v;
    }
    if (g == 0) rp[n] = total;
}

__global__ void scatter_edges(const int* __restrict__ row, const int* __restrict__ col,
                              const float* __restrict__ dinv, int* __restrict__ cur,
                              int* __restrict__ cols, float* __restrict__ wst, int e) {
    for (int i = blockIdx.x * blockDim.x + threadIdx.x; i < e; i += gridDim.x * blockDim.x) {
        int r = row[i], c = col[i];
        int slot = atomicAdd(&cur[r], 1);
        cols[slot] = c;
        wst[slot] = dinv[r] * dinv[c];
    }
}

// ---------------- precision-split pre-passes ----------------

__global__ void split_x(const float* __restrict__ x, unsigned short* __restrict__ hi,
                        unsigned short* __restrict__ lo, long n4) {
    long i = (long)blockIdx.x * 256 + threadIdx.x;
    if (i >= n4) return;
    float4 v = ((const float4*)x)[i];
    unsigned short h0 = f2bf_rn(v.x), h1 = f2bf_rn(v.y), h2 = f2bf_rn(v.z), h3 = f2bf_rn(v.w);
    ushort4 hv; hv.x = h0; hv.y = h1; hv.z = h2; hv.w = h3;
    ((ushort4*)hi)[i] = hv;
    ushort4 lv;
    lv.x = f2bf_rn(v.x - bf2f(h0));
    lv.y = f2bf_rn(v.y - bf2f(h1));
    lv.z = f2bf_rn(v.z - bf2f(h2));
    lv.w = f2bf_rn(v.w - bf2f(h3));
    ((ushort4*)lo)[i] = lv;
}

__global__ void split_w1t(const float* __restrict__ W1, unsigned short* __restrict__ hi,
                          unsigned short* __restrict__ lo) {
    int idx = blockIdx.x * 256 + threadIdx.x;  // 0 .. 512*512-1
    int k = idx >> 9, n = idx & 511;
    float w = W1[idx];
    unsigned short h = f2bf_rn(w);
    hi[(size_t)n * 512 + k] = h;
    lo[(size_t)n * 512 + k] = f2bf_rn(w - bf2f(h));
}

// W2 [512][40] f32 -> transposed padded hi/lo bf16 [48][512] (rows 40..47 zero)
__global__ void split_w2t(const float* __restrict__ W2, unsigned short* __restrict__ hi,
                          unsigned short* __restrict__ lo) {
    int idx = blockIdx.x * 256 + threadIdx.x;  // 0 .. 48*512-1
    int n = idx >> 9, k = idx & 511;
    float w = (n < 40) ? W2[(size_t)k * 40 + n] : 0.0f;
    unsigned short h = f2bf_rn(w);
    hi[(size_t)n * 512 + k] = h;
    lo[(size_t)n * 512 + k] = f2bf_rn(w - bf2f(h));
}

// ---------------- GEMM1 via MFMA (split-bf16, 3 terms) ----------------
// outputs H as bf16 hi/lo (split in registers; feeds gemm2_mfma)
__global__ __launch_bounds__(256) void gemm1_mfma(
    const unsigned short* __restrict__ Ahi, const unsigned short* __restrict__ Alo,
    const unsigned short* __restrict__ Bhi, const unsigned short* __restrict__ Blo,
    const float* __restrict__ b1, unsigned short* __restrict__ Hhi,
    unsigned short* __restrict__ Hlo, int rows_c) {
    __shared__ char smem[32768];  // Ahi 0, Alo 8192, Bhi 16384, Blo 24576 (each 128x32 bf16)
    const int tid = threadIdx.x;
    const int lane = tid & 63, wid = tid >> 6;
    const int wr = wid >> 1, wc = wid & 1;
    const int fr = lane & 15, kb = lane >> 4;
    const int bx = blockIdx.x, by = blockIdx.y;

    const int segbase = wid * 1024;
    const int off0 = segbase + (lane << 4);
    const int off1 = off0 + 4096;
    const int row0 = off0 >> 6, slot0 = (off0 >> 4) & 3;
    const int row1 = off1 >> 6, slot1 = (off1 >> 4) & 3;
    const int ss0 = slot0 ^ ((row0 >> 1) & 3);
    const int ss1 = slot1 ^ ((row1 >> 1) & 3);
    const int ar0 = min(by * 128 + row0, rows_c - 1);
    const int ar1 = min(by * 128 + row1, rows_c - 1);
    const int br0 = bx * 128 + row0;
    const int br1 = bx * 128 + row1;

    const unsigned short* pAh0 = Ahi + (size_t)ar0 * 512 + ss0 * 8;
    const unsigned short* pAh1 = Ahi + (size_t)ar1 * 512 + ss1 * 8;
    const unsigned short* pAl0 = Alo + (size_t)ar0 * 512 + ss0 * 8;
    const unsigned short* pAl1 = Alo + (size_t)ar1 * 512 + ss1 * 8;
    const unsigned short* pBh0 = Bhi + (size_t)br0 * 512 + ss0 * 8;
    const unsigned short* pBh1 = Bhi + (size_t)br1 * 512 + ss1 * 8;
    const unsigned short* pBl0 = Blo + (size_t)br0 * 512 + ss0 * 8;
    const unsigned short* pBl1 = Blo + (size_t)br1 * 512 + ss1 * 8;

    char* dst0 = smem + segbase;
    floatx4 acc[4][4] = {};

    for (int ks = 0; ks < 16; ++ks) {
        GLD16(pAh0, dst0);
        GLD16(pAh1, dst0 + 4096);
        GLD16(pAl0, dst0 + 8192);
        GLD16(pAl1, dst0 + 8192 + 4096);
        GLD16(pBh0, dst0 + 16384);
        GLD16(pBh1, dst0 + 16384 + 4096);
        GLD16(pBl0, dst0 + 24576);
        GLD16(pBl1, dst0 + 24576 + 4096);
        pAh0 += 32; pAh1 += 32; pAl0 += 32; pAl1 += 32;
        pBh0 += 32; pBh1 += 32; pBl0 += 32; pBl1 += 32;
        __syncthreads();

        short8b ah[4], al[4], bh[4], bl[4];
        #pragma unroll
        for (int m = 0; m < 4; ++m) {
            int rrow = wr * 64 + m * 16 + fr;
            int adr = rrow * 64 + ((kb ^ ((rrow >> 1) & 3)) << 4);
            ah[m] = *(const short8b*)(smem + adr);
            al[m] = *(const short8b*)(smem + 8192 + adr);
        }
        #pragma unroll
        for (int n = 0; n < 4; ++n) {
            int rrow = wc * 64 + n * 16 + fr;
            int adr = rrow * 64 + ((kb ^ ((rrow >> 1) & 3)) << 4);
            bh[n] = *(const short8b*)(smem + 16384 + adr);
            bl[n] = *(const short8b*)(smem + 24576 + adr);
        }
        #pragma unroll
        for (int m = 0; m < 4; ++m)
            #pragma unroll
            for (int n = 0; n < 4; ++n) {
                acc[m][n] = __builtin_amdgcn_mfma_f32_16x16x32_bf16(al[m], bh[n], acc[m][n], 0, 0, 0);
                acc[m][n] = __builtin_amdgcn_mfma_f32_16x16x32_bf16(ah[m], bl[n], acc[m][n], 0, 0, 0);
                acc[m][n] = __builtin_amdgcn_mfma_f32_16x16x32_bf16(ah[m], bh[n], acc[m][n], 0, 0, 0);
            }
        __syncthreads();
    }

    #pragma unroll
    for (int m = 0; m < 4; ++m) {
        int rbase = by * 128 + wr * 64 + m * 16 + kb * 4;
        #pragma unroll
        for (int n = 0; n < 4; ++n) {
            int c = bx * 128 + wc * 64 + n * 16 + fr;
            float bv = b1[c];
            #pragma unroll
            for (int q = 0; q < 4; ++q) {
                int rr = rbase + q;
                if (rr < rows_c) {
                    float v = fmaxf(acc[m][n][q] + bv, 0.0f);
                    unsigned short h = f2bf_rn(v);
                    Hhi[(size_t)rr * 512 + c] = h;
                    Hlo[(size_t)rr * 512 + c] = f2bf_rn(v - bf2f(h));
                }
            }
        }
    }
}

// ---------------- GEMM2 via MFMA (split-bf16, 3 terms) ----------------
// Z[rows,40] = Hsplit[rows,512] @ W2split[512,40] + b2. N padded to 48.
// 128x48 tile, BK=32, 4 waves; wave w -> rows [w*32, w*32+32) (2 m-frags x 3 n-frags).
__global__ __launch_bounds__(256) void gemm2_mfma(
    const unsigned short* __restrict__ Hhi, const unsigned short* __restrict__ Hlo,
    const unsigned short* __restrict__ W2thi, const unsigned short* __restrict__ W2tlo,
    const float* __restrict__ b2, float* __restrict__ Z,
    int row_start, int rows_c) {
    __shared__ char smem[22528];  // Ahi 0 (8192), Alo 8192, Bhi 16384 (3072), Blo 19456
    const int tid = threadIdx.x;
    const int lane = tid & 63, wid = tid >> 6;
    const int fr = lane & 15, kb = lane >> 4;
    const int by = blockIdx.x;

    // A staging: two 4096B regions (rows 0..63 / 64..127), thread -> 16B each
    const int rowA0 = tid >> 2, slotA = tid & 3;
    const int rowA1 = rowA0 + 64;
    const int ssA0 = slotA ^ ((rowA0 >> 1) & 3);
    const int ssA1 = slotA ^ ((rowA1 >> 1) & 3);
    const int arA0 = min(by * 128 + rowA0, rows_c - 1);
    const int arA1 = min(by * 128 + rowA1, rows_c - 1);
    const unsigned short* pAh0 = Hhi + (size_t)arA0 * 512 + ssA0 * 8;
    const unsigned short* pAh1 = Hhi + (size_t)arA1 * 512 + ssA1 * 8;
    const unsigned short* pAl0 = Hlo + (size_t)arA0 * 512 + ssA0 * 8;
    const unsigned short* pAl1 = Hlo + (size_t)arA1 * 512 + ssA1 * 8;
    // B staging: 3072B region, threads 0..191 (waves 0-2)
    const int rowB = tid >> 2;          // 0..47 for tid<192
    const int ssB = slotA ^ ((rowB >> 1) & 3);
    const unsigned short* pBh = W2thi + (size_t)rowB * 512 + ssB * 8;
    const unsigned short* pBl = W2tlo + (size_t)rowB * 512 + ssB * 8;

    char* dstA = smem + tid * 16;       // within region 0; +4096 region 1
    char* dstB = smem + 16384 + tid * 16;

    floatx4 acc[2][3] = {};

    for (int ks = 0; ks < 16; ++ks) {
        GLD16(pAh0, dstA);
        GLD16(pAh1, dstA + 4096);
        GLD16(pAl0, dstA + 8192);
        GLD16(pAl1, dstA + 8192 + 4096);
        if (tid < 192) {
            GLD16(pBh, dstB);
            GLD16(pBl, dstB + 3072);
        }
        pAh0 += 32; pAh1 += 32; pAl0 += 32; pAl1 += 32;
        pBh += 32; pBl += 32;
        __syncthreads();

        short8b ah[2], al[2], bh[3], bl[3];
        #pragma unroll
        for (int m = 0; m < 2; ++m) {
            int rrow = wid * 32 + m * 16 + fr;
            int adr = rrow * 64 + ((kb ^ ((rrow >> 1) & 3)) << 4);
            ah[m] = *(const short8b*)(smem + adr);
            al[m] = *(const short8b*)(smem + 8192 + adr);
        }
        #pragma unroll
        for (int n = 0; n < 3; ++n) {
            int brow = n * 16 + fr;
            int badr = brow * 64 + ((kb ^ ((brow >> 1) & 3)) << 4);
            bh[n] = *(const short8b*)(smem + 16384 + badr);
            bl[n] = *(const short8b*)(smem + 19456 + badr);
        }
        #pragma unroll
        for (int m = 0; m < 2; ++m)
            #pragma unroll
            for (int n = 0; n < 3; ++n) {
                acc[m][n] = __builtin_amdgcn_mfma_f32_16x16x32_bf16(al[m], bh[n], acc[m][n], 0, 0, 0);
                acc[m][n] = __builtin_amdgcn_mfma_f32_16x16x32_bf16(ah[m], bl[n], acc[m][n], 0, 0, 0);
                acc[m][n] = __builtin_amdgcn_mfma_f32_16x16x32_bf16(ah[m], bh[n], acc[m][n], 0, 0, 0);
            }
        __syncthreads();
    }

    // C/D: col=lane&15, row=(lane>>4)*4+q
    #pragma unroll
    for (int m = 0; m < 2; ++m) {
        int rbase = by * 128 + wid * 32 + m * 16 + kb * 4;
        #pragma unroll
        for (int n = 0; n < 3; ++n) {
            int c = n * 16 + fr;
            if (c < 40) {
                float bv = b2[c];
                #pragma unroll
                for (int q = 0; q < 4; ++q) {
                    int rr = rbase + q;
                    if (rr < rows_c)
                        Z[(size_t)(row_start + rr) * 40 + c] = acc[m][n][q] + bv;
                }
            }
        }
    }
}

// ---------------- propagation ----------------
// one wave per node; lanes 0..39 = features; edge loop unrolled 8/4/1 so
// 8 independent gathers are in flight per wave. fmaf order = sequential p-order.
__global__ __launch_bounds__(256) void prop(const float* __restrict__ zin,
                                            float* __restrict__ zout,
                                            const float* __restrict__ z0,
                                            const float* __restrict__ dinv,
                                            const int* __restrict__ rp,
                                            const int* __restrict__ cols,
                                            const float* __restrict__ wst) {
    int wid = (blockIdx.x * blockDim.x + threadIdx.x) >> 6;
    int lane = threadIdx.x & 63;
    if (wid >= NN || lane >= 40) return;
    const int start = rp[wid], end = rp[wid + 1];
    const float d = dinv[wid];
    const size_t fl = lane;
    float acc = d * d * zin[(size_t)wid * 40 + fl];
    int p = start;
    for (; p + 8 <= end; p += 8) {
        int c0 = cols[p + 0], c1 = cols[p + 1], c2 = cols[p + 2], c3 = cols[p + 3];
        int c4 = cols[p + 4], c5 = cols[p + 5], c6 = cols[p + 6], c7 = cols[p + 7];
        float w0 = wst[p + 0], w1 = wst[p + 1], w2 = wst[p + 2], w3 = wst[p + 3];
        float w4 = wst[p + 4], w5 = wst[p + 5], w6 = wst[p + 6], w7 = wst[p + 7];
        float v0 = zin[(size_t)c0 * 40 + fl];
        float v1 = zin[(size_t)c1 * 40 + fl];
        float v2 = zin[(size_t)c2 * 40 + fl];
        float v3 = zin[(size_t)c3 * 40 + fl];
        float v4 = zin[(size_t)c4 * 40 + fl];
        float v5 = zin[(size_t)c5 * 40 + fl];
        float v6 = zin[(size_t)c6 * 40 + fl];
        float v7 = zin[(size_t)c7 * 40 + fl];
        acc = fmaf(w0, v0, acc); acc = fmaf(w1, v1, acc);
        acc = fmaf(w2, v2, acc); acc = fmaf(w3, v3, acc);
        acc = fmaf(w4, v4, acc); acc = fmaf(w5, v5, acc);
        acc = fmaf(w6, v6, acc); acc = fmaf(w7, v7, acc);
    }
    for (; p + 4 <= end; p += 4) {
        int c0 = cols[p + 0], c1 = cols[p + 1], c2 = cols[p + 2], c3 = cols[p + 3];
        float w0 = wst[p + 0], w1 = wst[p + 1], w2 = wst[p + 2], w3 = wst[p + 3];
        float v0 = zin[(size_t)c0 * 40 + fl];
        float v1 = zin[(size_t)c1 * 40 + fl];
        float v2 = zin[(size_t)c2 * 40 + fl];
        float v3 = zin[(size_t)c3 * 40 + fl];
        acc = fmaf(w0, v0, acc); acc = fmaf(w1, v1, acc);
        acc = fmaf(w2, v2, acc); acc = fmaf(w3, v3, acc);
    }
    for (; p < end; ++p)
        acc = fmaf(wst[p], zin[(size_t)cols[p] * 40 + fl], acc);
    zout[(size_t)wid * 40 + fl] = 0.9f * acc + 0.1f * z0[(size_t)wid * 40 + fl];
}

// ---------------- launch ----------------

extern "C" void kernel_launch(void* const* d_in, const int* in_sizes, int n_in,
                              void* d_out, int out_size, void* d_ws, size_t ws_size,
                              hipStream_t stream) {
    const float* x  = (const float*)d_in[0];
    const float* W1 = (const float*)d_in[1];
    const float* b1 = (const float*)d_in[2];
    const float* W2 = (const float*)d_in[3];
    const float* b2 = (const float*)d_in[4];
    const int*   ei = (const int*)d_in[5];
    const int* erow = ei;          // targets
    const int* ecol = ei + NE;     // sources
    float* out = (float*)d_out;

    char* p = (char*)d_ws;
    auto alloc = [&](size_t bytes) { char* q = p; p += (bytes + 255) & ~(size_t)255; return q; };
    float* z0   = (float*)alloc((size_t)NN * 40 * 4);
    float* zA   = (float*)alloc((size_t)NN * 40 * 4);
    float* zB   = (float*)alloc((size_t)NN * 40 * 4);
    float* dinv = (float*)alloc((size_t)NN * 4);
    int* degc   = (int*)alloc((size_t)NN * 4);
    int* rp     = (int*)alloc((size_t)(NN + 1) * 4);
    int* cur    = (int*)alloc((size_t)NN * 4);
    int* bsums  = (int*)alloc(512 * 4);
    int* cols   = (int*)alloc((size_t)NE * 4);
    float* wst  = (float*)alloc((size_t)NE * 4);
    unsigned short* w1thi = (unsigned short*)alloc((size_t)512 * 512 * 2);
    unsigned short* w1tlo = (unsigned short*)alloc((size_t)512 * 512 * 2);
    unsigned short* w2thi = (unsigned short*)alloc((size_t)48 * 512 * 2);
    unsigned short* w2tlo = (unsigned short*)alloc((size_t)48 * 512 * 2);

    // per chunk row: xhi 1024 + xlo 1024 + Hhi 1024 + Hlo 1024 = 4096 B
    size_t used = (size_t)(p - (char*)d_ws);
    size_t remain = (ws_size > used) ? (ws_size - used - 1024) : 0;
    int CH = (int)((remain / 4096) & ~(size_t)127);
    if (CH > 25600) CH = 25600;
    if (CH < 128) CH = 128;
    unsigned short* xhi_c = (unsigned short*)alloc((size_t)CH * 512 * 2);
    unsigned short* xlo_c = (unsigned short*)alloc((size_t)CH * 512 * 2);
    unsigned short* hhi_c = (unsigned short*)alloc((size_t)CH * 512 * 2);
    unsigned short* hlo_c = (unsigned short*)alloc((size_t)CH * 512 * 2);

    const int nScanBlocks = (NN + 255) / 256;  // 391

    // graph build
    hipMemsetAsync(degc, 0, (size_t)NN * 4, stream);
    count_edges<<<1024, 256, 0, stream>>>(erow, degc, NE);
    compute_dinv<<<nScanBlocks, 256, 0, stream>>>(degc, dinv, NN);
    scan_block<<<nScanBlocks, 256, 0, stream>>>(degc, rp, bsums, NN);
    scan_small<<<1, 512, 0, stream>>>(bsums, nScanBlocks);
    scan_add<<<nScanBlocks, 256, 0, stream>>>(rp, bsums, cur, NN, NE);
    scatter_edges<<<1024, 256, 0, stream>>>(erow, ecol, dinv, cur, cols, wst, NE);

    // weight splits (once)
    split_w1t<<<(512 * 512) / 256, 256, 0, stream>>>(W1, w1thi, w1tlo);
    split_w2t<<<(48 * 512) / 256, 256, 0, stream>>>(W2, w2thi, w2tlo);

    // MLP in row chunks
    for (int rs = 0; rs < NN; rs += CH) {
        int re = min(rs + CH, NN);
        int rows = re - rs;
        long n4 = (long)rows * 128;
        split_x<<<(int)((n4 + 255) / 256), 256, 0, stream>>>(x + (size_t)rs * 512, xhi_c, xlo_c, n4);
        dim3 g1(4, (rows + 127) / 128);
        gemm1_mfma<<<g1, 256, 0, stream>>>(xhi_c, xlo_c, w1thi, w1tlo, b1, hhi_c, hlo_c, rows);
        gemm2_mfma<<<(rows + 127) / 128, 256, 0, stream>>>(hhi_c, hlo_c, w2thi, w2tlo, b2, z0, rs, rows);
    }

    // K=10 propagation, ping-pong, last writes d_out
    const float* zin = z0;
    for (int t = 0; t < KITER; ++t) {
        float* zo = (t == KITER - 1) ? out : ((t & 1) ? zB : zA);
        prop<<<(NN * 64 + 255) / 256, 256, 0, stream>>>(zin, zo, z0, dinv, rp, cols, wst);
        zin = zo;
    }
}

// Round 8
// 1392.812 us; speedup vs baseline: 2.3806x; 1.0495x over previous
//
#include <hip/hip_runtime.h>
#include <hip/hip_bf16.h>

#define NN 100000
#define FIN 512
#define HID 512
#define NC 40
#define NE 1600000
#define KITER 10

typedef __attribute__((ext_vector_type(8))) short short8b;
typedef __attribute__((ext_vector_type(4))) float floatx4;

#define GLD16(gp, lp) __builtin_amdgcn_global_load_lds( \
    (const __attribute__((address_space(1))) void*)(gp), \
    (__attribute__((address_space(3))) void*)(lp), 16, 0, 0)

__device__ __forceinline__ unsigned short f2bf_rn(float f) {
    union { float f; unsigned u; } x; x.f = f;
    unsigned r = x.u + 0x7fffu + ((x.u >> 16) & 1u);
    return (unsigned short)(r >> 16);
}
__device__ __forceinline__ float bf2f(unsigned short h) {
    union { unsigned u; float f; } y; y.u = ((unsigned)h) << 16;
    return y.f;
}

// ---------------- graph build ----------------

__global__ void count_edges(const int* __restrict__ row, int* __restrict__ degc, int e) {
    for (int i = blockIdx.x * blockDim.x + threadIdx.x; i < e; i += gridDim.x * blockDim.x)
        atomicAdd(&degc[row[i]], 1);
}

__global__ void compute_dinv(const int* __restrict__ degc, float* __restrict__ dinv, int n) {
    int g = blockIdx.x * blockDim.x + threadIdx.x;
    if (g < n) dinv[g] = 1.0f / sqrtf((float)(degc[g] + 1));  // +1 self-loop
}

__global__ void scan_block(const int* __restrict__ in, int* __restrict__ outExc,
                           int* __restrict__ bsum, int n) {
    __shared__ int s[256];
    int t = threadIdx.x, g = blockIdx.x * 256 + t;
    int v = (g < n) ? in[g] : 0;
    s[t] = v; __syncthreads();
    for (int off = 1; off < 256; off <<= 1) {
        int x = (t >= off) ? s[t - off] : 0;
        __syncthreads();
        s[t] += x;
        __syncthreads();
    }
    if (g < n) outExc[g] = s[t] - v;
    if (t == 255) bsum[blockIdx.x] = s[255];
}

__global__ void scan_small(int* __restrict__ data, int n) {  // n <= 512, exclusive in-place
    __shared__ int s[512];
    int t = threadIdx.x;
    int v = (t < n) ? data[t] : 0;
    s[t] = v; __syncthreads();
    for (int off = 1; off < 512; off <<= 1) {
        int x = (t >= off) ? s[t - off] : 0;
        __syncthreads();
        s[t] += x;
        __syncthreads();
    }
    if (t < n) data[t] = s[t] - v;
}

__global__ void scan_add(int* __restrict__ rp, const int* __restrict__ bsum,
                         int* __restrict__ cur, int n, int total) {
    int g = blockIdx.x * 256 + threadIdx.x;
    if (g < n) {
        int v = rp[g] + bsum[blockIdx.x];
        rp[g] = v;
        cur[g] = v;
    }
    if (g == 0) rp[n] = total;
}

__global__ void scatter_edges(const int* __restrict__ row, const int* __restrict__ col,
                              const float* __restrict__ dinv, int* __restrict__ cur,
                              int* __restrict__ cols, float* __restrict__ wst, int e) {
    for (int i = blockIdx.x * blockDim.x + threadIdx.x; i < e; i += gridDim.x * blockDim.x) {
        int r = row[i], c = col[i];
        int slot = atomicAdd(&cur[r], 1);
        cols[slot] = c;
        wst[slot] = dinv[r] * dinv[c];
    }
}

// ---------------- precision-split pre-passes ----------------

__global__ void split_x(const float* __restrict__ x, unsigned short* __restrict__ hi,
                        unsigned short* __restrict__ lo, long n4) {
    long i = (long)blockIdx.x * 256 + threadIdx.x;
    if (i >= n4) return;
    float4 v = ((const float4*)x)[i];
    unsigned short h0 = f2bf_rn(v.x), h1 = f2bf_rn(v.y), h2 = f2bf_rn(v.z), h3 = f2bf_rn(v.w);
    ushort4 hv; hv.x = h0; hv.y = h1; hv.z = h2; hv.w = h3;
    ((ushort4*)hi)[i] = hv;
    ushort4 lv;
    lv.x = f2bf_rn(v.x - bf2f(h0));
    lv.y = f2bf_rn(v.y - bf2f(h1));
    lv.z = f2bf_rn(v.z - bf2f(h2));
    lv.w = f2bf_rn(v.w - bf2f(h3));
    ((ushort4*)lo)[i] = lv;
}

__global__ void split_w1t(const float* __restrict__ W1, unsigned short* __restrict__ hi,
                          unsigned short* __restrict__ lo) {
    int idx = blockIdx.x * 256 + threadIdx.x;  // 0 .. 512*512-1
    int k = idx >> 9, n = idx & 511;
    float w = W1[idx];
    unsigned short h = f2bf_rn(w);
    hi[(size_t)n * 512 + k] = h;
    lo[(size_t)n * 512 + k] = f2bf_rn(w - bf2f(h));
}

// W2 [512][40] f32 -> transposed padded hi/lo bf16 [48][512] (rows 40..47 zero)
__global__ void split_w2t(const float* __restrict__ W2, unsigned short* __restrict__ hi,
                          unsigned short* __restrict__ lo) {
    int idx = blockIdx.x * 256 + threadIdx.x;  // 0 .. 48*512-1
    int n = idx >> 9, k = idx & 511;
    float w = (n < 40) ? W2[(size_t)k * 40 + n] : 0.0f;
    unsigned short h = f2bf_rn(w);
    hi[(size_t)n * 512 + k] = h;
    lo[(size_t)n * 512 + k] = f2bf_rn(w - bf2f(h));
}

// ---------------- GEMM1 via MFMA (split-bf16, 3 terms) ----------------
// outputs H as bf16 hi/lo (split in registers; feeds gemm2_mfma)
__global__ __launch_bounds__(256) void gemm1_mfma(
    const unsigned short* __restrict__ Ahi, const unsigned short* __restrict__ Alo,
    const unsigned short* __restrict__ Bhi, const unsigned short* __restrict__ Blo,
    const float* __restrict__ b1, unsigned short* __restrict__ Hhi,
    unsigned short* __restrict__ Hlo, int rows_c) {
    __shared__ char smem[32768];  // Ahi 0, Alo 8192, Bhi 16384, Blo 24576 (each 128x32 bf16)
    const int tid = threadIdx.x;
    const int lane = tid & 63, wid = tid >> 6;
    const int wr = wid >> 1, wc = wid & 1;
    const int fr = lane & 15, kb = lane >> 4;
    const int bx = blockIdx.x, by = blockIdx.y;

    const int segbase = wid * 1024;
    const int off0 = segbase + (lane << 4);
    const int off1 = off0 + 4096;
    const int row0 = off0 >> 6, slot0 = (off0 >> 4) & 3;
    const int row1 = off1 >> 6, slot1 = (off1 >> 4) & 3;
    const int ss0 = slot0 ^ ((row0 >> 1) & 3);
    const int ss1 = slot1 ^ ((row1 >> 1) & 3);
    const int ar0 = min(by * 128 + row0, rows_c - 1);
    const int ar1 = min(by * 128 + row1, rows_c - 1);
    const int br0 = bx * 128 + row0;
    const int br1 = bx * 128 + row1;

    const unsigned short* pAh0 = Ahi + (size_t)ar0 * 512 + ss0 * 8;
    const unsigned short* pAh1 = Ahi + (size_t)ar1 * 512 + ss1 * 8;
    const unsigned short* pAl0 = Alo + (size_t)ar0 * 512 + ss0 * 8;
    const unsigned short* pAl1 = Alo + (size_t)ar1 * 512 + ss1 * 8;
    const unsigned short* pBh0 = Bhi + (size_t)br0 * 512 + ss0 * 8;
    const unsigned short* pBh1 = Bhi + (size_t)br1 * 512 + ss1 * 8;
    const unsigned short* pBl0 = Blo + (size_t)br0 * 512 + ss0 * 8;
    const unsigned short* pBl1 = Blo + (size_t)br1 * 512 + ss1 * 8;

    char* dst0 = smem + segbase;
    floatx4 acc[4][4] = {};

    for (int ks = 0; ks < 16; ++ks) {
        GLD16(pAh0, dst0);
        GLD16(pAh1, dst0 + 4096);
        GLD16(pAl0, dst0 + 8192);
        GLD16(pAl1, dst0 + 8192 + 4096);
        GLD16(pBh0, dst0 + 16384);
        GLD16(pBh1, dst0 + 16384 + 4096);
        GLD16(pBl0, dst0 + 24576);
        GLD16(pBl1, dst0 + 24576 + 4096);
        pAh0 += 32; pAh1 += 32; pAl0 += 32; pAl1 += 32;
        pBh0 += 32; pBh1 += 32; pBl0 += 32; pBl1 += 32;
        __syncthreads();

        short8b ah[4], al[4], bh[4], bl[4];
        #pragma unroll
        for (int m = 0; m < 4; ++m) {
            int rrow = wr * 64 + m * 16 + fr;
            int adr = rrow * 64 + ((kb ^ ((rrow >> 1) & 3)) << 4);
            ah[m] = *(const short8b*)(smem + adr);
            al[m] = *(const short8b*)(smem + 8192 + adr);
        }
        #pragma unroll
        for (int n = 0; n < 4; ++n) {
            int rrow = wc * 64 + n * 16 + fr;
            int adr = rrow * 64 + ((kb ^ ((rrow >> 1) & 3)) << 4);
            bh[n] = *(const short8b*)(smem + 16384 + adr);
            bl[n] = *(const short8b*)(smem + 24576 + adr);
        }
        #pragma unroll
        for (int m = 0; m < 4; ++m)
            #pragma unroll
            for (int n = 0; n < 4; ++n) {
                acc[m][n] = __builtin_amdgcn_mfma_f32_16x16x32_bf16(al[m], bh[n], acc[m][n], 0, 0, 0);
                acc[m][n] = __builtin_amdgcn_mfma_f32_16x16x32_bf16(ah[m], bl[n], acc[m][n], 0, 0, 0);
                acc[m][n] = __builtin_amdgcn_mfma_f32_16x16x32_bf16(ah[m], bh[n], acc[m][n], 0, 0, 0);
            }
        __syncthreads();
    }

    #pragma unroll
    for (int m = 0; m < 4; ++m) {
        int rbase = by * 128 + wr * 64 + m * 16 + kb * 4;
        #pragma unroll
        for (int n = 0; n < 4; ++n) {
            int c = bx * 128 + wc * 64 + n * 16 + fr;
            float bv = b1[c];
            #pragma unroll
            for (int q = 0; q < 4; ++q) {
                int rr = rbase + q;
                if (rr < rows_c) {
                    float v = fmaxf(acc[m][n][q] + bv, 0.0f);
                    unsigned short h = f2bf_rn(v);
                    Hhi[(size_t)rr * 512 + c] = h;
                    Hlo[(size_t)rr * 512 + c] = f2bf_rn(v - bf2f(h));
                }
            }
        }
    }
}

// ---------------- GEMM2 via MFMA (split-bf16, 3 terms) ----------------
// Z[rows,40] = Hsplit[rows,512] @ W2split[512,40] + b2. N padded to 48.
__global__ __launch_bounds__(256) void gemm2_mfma(
    const unsigned short* __restrict__ Hhi, const unsigned short* __restrict__ Hlo,
    const unsigned short* __restrict__ W2thi, const unsigned short* __restrict__ W2tlo,
    const float* __restrict__ b2, float* __restrict__ Z,
    int row_start, int rows_c) {
    __shared__ char smem[22528];  // Ahi 0 (8192), Alo 8192, Bhi 16384 (3072), Blo 19456
    const int tid = threadIdx.x;
    const int lane = tid & 63, wid = tid >> 6;
    const int fr = lane & 15, kb = lane >> 4;
    const int by = blockIdx.x;

    const int rowA0 = tid >> 2, slotA = tid & 3;
    const int rowA1 = rowA0 + 64;
    const int ssA0 = slotA ^ ((rowA0 >> 1) & 3);
    const int ssA1 = slotA ^ ((rowA1 >> 1) & 3);
    const int arA0 = min(by * 128 + rowA0, rows_c - 1);
    const int arA1 = min(by * 128 + rowA1, rows_c - 1);
    const unsigned short* pAh0 = Hhi + (size_t)arA0 * 512 + ssA0 * 8;
    const unsigned short* pAh1 = Hhi + (size_t)arA1 * 512 + ssA1 * 8;
    const unsigned short* pAl0 = Hlo + (size_t)arA0 * 512 + ssA0 * 8;
    const unsigned short* pAl1 = Hlo + (size_t)arA1 * 512 + ssA1 * 8;
    const int rowB = tid >> 2;          // 0..47 for tid<192
    const int ssB = slotA ^ ((rowB >> 1) & 3);
    const unsigned short* pBh = W2thi + (size_t)rowB * 512 + ssB * 8;
    const unsigned short* pBl = W2tlo + (size_t)rowB * 512 + ssB * 8;

    char* dstA = smem + tid * 16;       // within region 0; +4096 region 1
    char* dstB = smem + 16384 + tid * 16;

    floatx4 acc[2][3] = {};

    for (int ks = 0; ks < 16; ++ks) {
        GLD16(pAh0, dstA);
        GLD16(pAh1, dstA + 4096);
        GLD16(pAl0, dstA + 8192);
        GLD16(pAl1, dstA + 8192 + 4096);
        if (tid < 192) {
            GLD16(pBh, dstB);
            GLD16(pBl, dstB + 3072);
        }
        pAh0 += 32; pAh1 += 32; pAl0 += 32; pAl1 += 32;
        pBh += 32; pBl += 32;
        __syncthreads();

        short8b ah[2], al[2], bh[3], bl[3];
        #pragma unroll
        for (int m = 0; m < 2; ++m) {
            int rrow = wid * 32 + m * 16 + fr;
            int adr = rrow * 64 + ((kb ^ ((rrow >> 1) & 3)) << 4);
            ah[m] = *(const short8b*)(smem + adr);
            al[m] = *(const short8b*)(smem + 8192 + adr);
        }
        #pragma unroll
        for (int n = 0; n < 3; ++n) {
            int brow = n * 16 + fr;
            int badr = brow * 64 + ((kb ^ ((brow >> 1) & 3)) << 4);
            bh[n] = *(const short8b*)(smem + 16384 + badr);
            bl[n] = *(const short8b*)(smem + 19456 + badr);
        }
        #pragma unroll
        for (int m = 0; m < 2; ++m)
            #pragma unroll
            for (int n = 0; n < 3; ++n) {
                acc[m][n] = __builtin_amdgcn_mfma_f32_16x16x32_bf16(al[m], bh[n], acc[m][n], 0, 0, 0);
                acc[m][n] = __builtin_amdgcn_mfma_f32_16x16x32_bf16(ah[m], bl[n], acc[m][n], 0, 0, 0);
                acc[m][n] = __builtin_amdgcn_mfma_f32_16x16x32_bf16(ah[m], bh[n], acc[m][n], 0, 0, 0);
            }
        __syncthreads();
    }

    #pragma unroll
    for (int m = 0; m < 2; ++m) {
        int rbase = by * 128 + wid * 32 + m * 16 + kb * 4;
        #pragma unroll
        for (int n = 0; n < 3; ++n) {
            int c = n * 16 + fr;
            if (c < 40) {
                float bv = b2[c];
                #pragma unroll
                for (int q = 0; q < 4; ++q) {
                    int rr = rbase + q;
                    if (rr < rows_c)
                        Z[(size_t)(row_start + rr) * 40 + c] = acc[m][n][q] + bv;
                }
            }
        }
    }
}

// ---------------- propagation ----------------
// 6 nodes per wave: lanes [sub*10, sub*10+10) handle node (gw*6+sub), each lane
// carries a float4 (4 features). 94% lane use, 16 B/lane gathers, 8-deep unroll
// -> up to 48 row-gathers in flight per wave. Per-feature fmaf chain keeps the
// sequential edge order (bitwise-identical to the 1-node/wave version).
__global__ __launch_bounds__(256) void prop(const float* __restrict__ zin,
                                            float* __restrict__ zout,
                                            const float* __restrict__ z0,
                                            const float* __restrict__ dinv,
                                            const int* __restrict__ rp,
                                            const int* __restrict__ cols,
                                            const float* __restrict__ wst) {
    int gw = (blockIdx.x * 256 + threadIdx.x) >> 6;
    int lane = threadIdx.x & 63;
    int sub = lane / 10;              // 0..5 active, 6 for lanes 60..63
    int fl4 = lane - sub * 10;        // float4 slot 0..9
    if (sub >= 6) return;
    int node = gw * 6 + sub;
    if (node >= NN) return;
    const int start = rp[node], end = rp[node + 1];
    const float d = dinv[node];
    const float dd = d * d;

    float4 a = ((const float4*)(zin + (size_t)node * 40))[fl4];
    float4 acc;
    acc.x = dd * a.x; acc.y = dd * a.y; acc.z = dd * a.z; acc.w = dd * a.w;

    int p = start;
    for (; p + 8 <= end; p += 8) {
        int c0 = cols[p + 0], c1 = cols[p + 1], c2 = cols[p + 2], c3 = cols[p + 3];
        int c4 = cols[p + 4], c5 = cols[p + 5], c6 = cols[p + 6], c7 = cols[p + 7];
        float w0 = wst[p + 0], w1 = wst[p + 1], w2 = wst[p + 2], w3 = wst[p + 3];
        float w4 = wst[p + 4], w5 = wst[p + 5], w6 = wst[p + 6], w7 = wst[p + 7];
        float4 v0 = ((const float4*)(zin + (size_t)c0 * 40))[fl4];
        float4 v1 = ((const float4*)(zin + (size_t)c1 * 40))[fl4];
        float4 v2 = ((const float4*)(zin + (size_t)c2 * 40))[fl4];
        float4 v3 = ((const float4*)(zin + (size_t)c3 * 40))[fl4];
        float4 v4 = ((const float4*)(zin + (size_t)c4 * 40))[fl4];
        float4 v5 = ((const float4*)(zin + (size_t)c5 * 40))[fl4];
        float4 v6 = ((const float4*)(zin + (size_t)c6 * 40))[fl4];
        float4 v7 = ((const float4*)(zin + (size_t)c7 * 40))[fl4];
        acc.x = fmaf(w0, v0.x, acc.x); acc.y = fmaf(w0, v0.y, acc.y);
        acc.z = fmaf(w0, v0.z, acc.z); acc.w = fmaf(w0, v0.w, acc.w);
        acc.x = fmaf(w1, v1.x, acc.x); acc.y = fmaf(w1, v1.y, acc.y);
        acc.z = fmaf(w1, v1.z, acc.z); acc.w = fmaf(w1, v1.w, acc.w);
        acc.x = fmaf(w2, v2.x, acc.x); acc.y = fmaf(w2, v2.y, acc.y);
        acc.z = fmaf(w2, v2.z, acc.z); acc.w = fmaf(w2, v2.w, acc.w);
        acc.x = fmaf(w3, v3.x, acc.x); acc.y = fmaf(w3, v3.y, acc.y);
        acc.z = fmaf(w3, v3.z, acc.z); acc.w = fmaf(w3, v3.w, acc.w);
        acc.x = fmaf(w4, v4.x, acc.x); acc.y = fmaf(w4, v4.y, acc.y);
        acc.z = fmaf(w4, v4.z, acc.z); acc.w = fmaf(w4, v4.w, acc.w);
        acc.x = fmaf(w5, v5.x, acc.x); acc.y = fmaf(w5, v5.y, acc.y);
        acc.z = fmaf(w5, v5.z, acc.z); acc.w = fmaf(w5, v5.w, acc.w);
        acc.x = fmaf(w6, v6.x, acc.x); acc.y = fmaf(w6, v6.y, acc.y);
        acc.z = fmaf(w6, v6.z, acc.z); acc.w = fmaf(w6, v6.w, acc.w);
        acc.x = fmaf(w7, v7.x, acc.x); acc.y = fmaf(w7, v7.y, acc.y);
        acc.z = fmaf(w7, v7.z, acc.z); acc.w = fmaf(w7, v7.w, acc.w);
    }
    for (; p + 4 <= end; p += 4) {
        int c0 = cols[p + 0], c1 = cols[p + 1], c2 = cols[p + 2], c3 = cols[p + 3];
        float w0 = wst[p + 0], w1 = wst[p + 1], w2 = wst[p + 2], w3 = wst[p + 3];
        float4 v0 = ((const float4*)(zin + (size_t)c0 * 40))[fl4];
        float4 v1 = ((const float4*)(zin + (size_t)c1 * 40))[fl4];
        float4 v2 = ((const float4*)(zin + (size_t)c2 * 40))[fl4];
        float4 v3 = ((const float4*)(zin + (size_t)c3 * 40))[fl4];
        acc.x = fmaf(w0, v0.x, acc.x); acc.y = fmaf(w0, v0.y, acc.y);
        acc.z = fmaf(w0, v0.z, acc.z); acc.w = fmaf(w0, v0.w, acc.w);
        acc.x = fmaf(w1, v1.x, acc.x); acc.y = fmaf(w1, v1.y, acc.y);
        acc.z = fmaf(w1, v1.z, acc.z); acc.w = fmaf(w1, v1.w, acc.w);
        acc.x = fmaf(w2, v2.x, acc.x); acc.y = fmaf(w2, v2.y, acc.y);
        acc.z = fmaf(w2, v2.z, acc.z); acc.w = fmaf(w2, v2.w, acc.w);
        acc.x = fmaf(w3, v3.x, acc.x); acc.y = fmaf(w3, v3.y, acc.y);
        acc.z = fmaf(w3, v3.z, acc.z); acc.w = fmaf(w3, v3.w, acc.w);
    }
    for (; p < end; ++p) {
        int c = cols[p]; float w = wst[p];
        float4 v = ((const float4*)(zin + (size_t)c * 40))[fl4];
        acc.x = fmaf(w, v.x, acc.x); acc.y = fmaf(w, v.y, acc.y);
        acc.z = fmaf(w, v.z, acc.z); acc.w = fmaf(w, v.w, acc.w);
    }
    float4 zv = ((const float4*)(z0 + (size_t)node * 40))[fl4];
    float4 o;
    o.x = 0.9f * acc.x + 0.1f * zv.x;
    o.y = 0.9f * acc.y + 0.1f * zv.y;
    o.z = 0.9f * acc.z + 0.1f * zv.z;
    o.w = 0.9f * acc.w + 0.1f * zv.w;
    ((float4*)(zout + (size_t)node * 40))[fl4] = o;
}

// ---------------- launch ----------------

extern "C" void kernel_launch(void* const* d_in, const int* in_sizes, int n_in,
                              void* d_out, int out_size, void* d_ws, size_t ws_size,
                              hipStream_t stream) {
    const float* x  = (const float*)d_in[0];
    const float* W1 = (const float*)d_in[1];
    const float* b1 = (const float*)d_in[2];
    const float* W2 = (const float*)d_in[3];
    const float* b2 = (const float*)d_in[4];
    const int*   ei = (const int*)d_in[5];
    const int* erow = ei;          // targets
    const int* ecol = ei + NE;     // sources
    float* out = (float*)d_out;

    char* p = (char*)d_ws;
    auto alloc = [&](size_t bytes) { char* q = p; p += (bytes + 255) & ~(size_t)255; return q; };
    float* z0   = (float*)alloc((size_t)NN * 40 * 4);
    float* zA   = (float*)alloc((size_t)NN * 40 * 4);
    float* zB   = (float*)alloc((size_t)NN * 40 * 4);
    float* dinv = (float*)alloc((size_t)NN * 4);
    int* degc   = (int*)alloc((size_t)NN * 4);
    int* rp     = (int*)alloc((size_t)(NN + 1) * 4);
    int* cur    = (int*)alloc((size_t)NN * 4);
    int* bsums  = (int*)alloc(512 * 4);
    int* cols   = (int*)alloc((size_t)NE * 4);
    float* wst  = (float*)alloc((size_t)NE * 4);
    unsigned short* w1thi = (unsigned short*)alloc((size_t)512 * 512 * 2);
    unsigned short* w1tlo = (unsigned short*)alloc((size_t)512 * 512 * 2);
    unsigned short* w2thi = (unsigned short*)alloc((size_t)48 * 512 * 2);
    unsigned short* w2tlo = (unsigned short*)alloc((size_t)48 * 512 * 2);

    // per chunk row: xhi 1024 + xlo 1024 + Hhi 1024 + Hlo 1024 = 4096 B
    size_t used = (size_t)(p - (char*)d_ws);
    size_t remain = (ws_size > used) ? (ws_size - used - 1024) : 0;
    int CH = (int)((remain / 4096) & ~(size_t)127);
    if (CH > 25600) CH = 25600;
    if (CH < 128) CH = 128;
    unsigned short* xhi_c = (unsigned short*)alloc((size_t)CH * 512 * 2);
    unsigned short* xlo_c = (unsigned short*)alloc((size_t)CH * 512 * 2);
    unsigned short* hhi_c = (unsigned short*)alloc((size_t)CH * 512 * 2);
    unsigned short* hlo_c = (unsigned short*)alloc((size_t)CH * 512 * 2);

    const int nScanBlocks = (NN + 255) / 256;  // 391

    // graph build
    hipMemsetAsync(degc, 0, (size_t)NN * 4, stream);
    count_edges<<<1024, 256, 0, stream>>>(erow, degc, NE);
    compute_dinv<<<nScanBlocks, 256, 0, stream>>>(degc, dinv, NN);
    scan_block<<<nScanBlocks, 256, 0, stream>>>(degc, rp, bsums, NN);
    scan_small<<<1, 512, 0, stream>>>(bsums, nScanBlocks);
    scan_add<<<nScanBlocks, 256, 0, stream>>>(rp, bsums, cur, NN, NE);
    scatter_edges<<<1024, 256, 0, stream>>>(erow, ecol, dinv, cur, cols, wst, NE);

    // weight splits (once)
    split_w1t<<<(512 * 512) / 256, 256, 0, stream>>>(W1, w1thi, w1tlo);
    split_w2t<<<(48 * 512) / 256, 256, 0, stream>>>(W2, w2thi, w2tlo);

    // MLP in row chunks
    for (int rs = 0; rs < NN; rs += CH) {
        int re = min(rs + CH, NN);
        int rows = re - rs;
        long n4 = (long)rows * 128;
        split_x<<<(int)((n4 + 255) / 256), 256, 0, stream>>>(x + (size_t)rs * 512, xhi_c, xlo_c, n4);
        dim3 g1(4, (rows + 127) / 128);
        gemm1_mfma<<<g1, 256, 0, stream>>>(xhi_c, xlo_c, w1thi, w1tlo, b1, hhi_c, hlo_c, rows);
        gemm2_mfma<<<(rows + 127) / 128, 256, 0, stream>>>(hhi_c, hlo_c, w2thi, w2tlo, b2, z0, rs, rows);
    }

    // K=10 propagation, ping-pong, last writes d_out
    // 256 threads = 4 waves = 24 nodes per block
    const int propBlocks = (NN + 23) / 24;
    const float* zin = z0;
    for (int t = 0; t < KITER; ++t) {
        float* zo = (t == KITER - 1) ? out : ((t & 1) ? zB : zA);
        prop<<<propBlocks, 256, 0, stream>>>(zin, zo, z0, dinv, rp, cols, wst);
        zin = zo;
    }
}